// Round 7
// baseline (1022.803 us; speedup 1.0000x reference)
//
#include <hip/hip_runtime.h>
#include <math.h>

static constexpr int BB   = 256;   // batch
static constexpr int IHN  = 200;   // internal tokens
static constexpr int ILN  = 6;     // internal feature dim
static constexpr int LHN  = 100;   // leaf tokens
static constexpr int EE   = 256;   // embed dim
static constexpr int FFH  = 512;   // ff hidden
static constexpr int NL   = 2;     // layers
static constexpr int GG   = 301;   // real tokens
static constexpr int GP   = 320;   // padded tokens (10 x 32)
static constexpr int MT   = BB * GP;  // 81920 total token rows (640 x 128)

typedef unsigned short u16;
typedef short bf16x8 __attribute__((ext_vector_type(8)));
typedef float f32x4 __attribute__((ext_vector_type(4)));

#define MFMA(a, b, c) __builtin_amdgcn_mfma_f32_16x16x32_bf16((a), (b), (c), 0, 0, 0)

__device__ __forceinline__ u16 f2bf(float f) {
    union { float f; unsigned u; } v; v.f = f;
    unsigned r = v.u + 0x7FFFu + ((v.u >> 16) & 1u);
    return (u16)(r >> 16);
}

// ---------------- wave/block reduction helpers (wave = 64) ----------------
__device__ __forceinline__ float waveReduceSum(float v) {
    for (int o = 32; o > 0; o >>= 1) v += __shfl_down(v, o, 64);
    return v;
}
__device__ __forceinline__ float waveReduceMax(float v) {
    for (int o = 32; o > 0; o >>= 1) v = fmaxf(v, __shfl_down(v, o, 64));
    return v;
}
__device__ __forceinline__ float blockReduceSum(float v, float* red) {
    int lane = threadIdx.x & 63;
    int w    = threadIdx.x >> 6;
    int nw   = (blockDim.x + 63) >> 6;
    v = waveReduceSum(v);
    if (lane == 0) red[w] = v;
    __syncthreads();
    if (threadIdx.x < 64) {
        float x = (lane < nw) ? red[lane] : 0.0f;
        x = waveReduceSum(x);
        if (lane == 0) red[0] = x;
    }
    __syncthreads();
    float r = red[0];
    __syncthreads();
    return r;
}
__device__ __forceinline__ float blockReduceMax(float v, float* red) {
    int lane = threadIdx.x & 63;
    int w    = threadIdx.x >> 6;
    int nw   = (blockDim.x + 63) >> 6;
    v = waveReduceMax(v);
    if (lane == 0) red[w] = v;
    __syncthreads();
    if (threadIdx.x < 64) {
        float x = (lane < nw) ? red[lane] : -INFINITY;
        x = waveReduceMax(x);
        if (lane == 0) red[0] = x;
    }
    __syncthreads();
    float r = red[0];
    __syncthreads();
    return r;
}

// --------- staging: global -> LDS tile [rows][64] bf16, XOR-swizzled ---------
__device__ __forceinline__ void stage_swz(const u16* src, int strideShorts, int k0,
                                          u16* ldsTile, int nChunks, int wave,
                                          int nWaves, int lane)
{
    for (int c = wave; c < nChunks; c += nWaves) {
        int o = c * 1024 + lane * 16;
        int row = o >> 7;
        int cb = (o & 127) ^ ((row & 7) << 4);
        const u16* g = src + (size_t)row * strideShorts + k0 + (cb >> 1);
        __builtin_amdgcn_global_load_lds(
            (const __attribute__((address_space(1))) unsigned int*)g,
            (__attribute__((address_space(3))) unsigned int*)((char*)ldsTile + c * 1024),
            16, 0, 0);
    }
}

__device__ __forceinline__ bf16x8 lds_frag(const u16* tile, int row, int kk, int q)
{
    int cb = (kk * 64 + q * 16) ^ ((row & 7) << 4);
    return *(const bf16x8*)((const char*)tile + row * 128 + cb);
}

// ------------- prep: transpose encoder weights to bf16 [N][K] -------------
__global__ __launch_bounds__(256) void prep_kernel(
    const float* __restrict__ wq, const float* __restrict__ wk,
    const float* __restrict__ wv, const float* __restrict__ wo,
    const float* __restrict__ wf1, const float* __restrict__ wf2,
    u16* __restrict__ wT)
{
    int l = blockIdx.y / 6, m = blockIdx.y % 6;
    int idx = blockIdx.x * 256 + threadIdx.x;
    u16* dst = wT + (size_t)l * 524288;
    if (m < 4) {
        if (idx >= EE * EE) return;
        const float* src = (m == 0 ? wq : m == 1 ? wk : m == 2 ? wv : wo) + (size_t)l * EE * EE;
        int r = idx >> 8, c = idx & 255;
        dst[m * 65536 + idx] = f2bf(src[(size_t)c * EE + r]);
    } else if (m == 4) {
        if (idx >= FFH * EE) return;
        const float* src = wf1 + (size_t)l * EE * FFH;
        int r = idx >> 8, c = idx & 255;
        dst[262144 + idx] = f2bf(src[(size_t)c * FFH + r]);
    } else {
        if (idx >= EE * FFH) return;
        const float* src = wf2 + (size_t)l * FFH * EE;
        int r = idx >> 9, c = idx & 511;
        dst[393216 + idx] = f2bf(src[(size_t)c * EE + r]);
    }
}

// ---------- embed (segment version): 32 tokens/block, w2 col in regs ----------
template<int IND, int SEG, int G0>
__global__ __launch_bounds__(256) void embed_seg(
    const float* __restrict__ obs,
    const float* __restrict__ w1, const float* __restrict__ b1,
    const float* __restrict__ w2, const float* __restrict__ b2,
    float* __restrict__ h, u16* __restrict__ hb)
{
    __shared__ float xs[32][9];
    __shared__ float hid[32][33];
    int t = threadIdx.x;
    int fi0 = blockIdx.x * 32;

    for (int p = t; p < 32 * 9; p += 256) {
        int tok = p / 9, f = p % 9;
        int fi = fi0 + tok;
        int b = fi / SEG, g = G0 + fi % SEG;
        xs[tok][f] = obs[((size_t)b * GG + g) * 9 + f];
    }
    __syncthreads();

    #pragma unroll
    for (int p = 0; p < 4; p++) {
        int idx = p * 256 + t;
        int tok = idx >> 5, hcol = idx & 31;
        float a = b1[hcol];
        #pragma unroll
        for (int i = 0; i < IND; i++) a += xs[tok][i] * w1[i * 32 + hcol];
        hid[tok][hcol] = (a > 0.0f) ? a : 0.01f * a;
    }
    __syncthreads();

    float w2c[32];
    #pragma unroll
    for (int j = 0; j < 32; j++) w2c[j] = w2[j * EE + t];
    float bb = b2[t];
    for (int tok = 0; tok < 32; tok++) {
        int fi = fi0 + tok;
        int b = fi / SEG, g = G0 + fi % SEG;
        float a = bb;
        #pragma unroll
        for (int j = 0; j < 32; j++) a += hid[tok][j] * w2c[j];
        size_t o = ((size_t)b * GP + g) * EE + t;
        h[o] = a; hb[o] = f2bf(a);
    }
}

// zero the pad rows g in [GG, GP)
__global__ __launch_bounds__(256) void pad_kernel(float* __restrict__ h, u16* __restrict__ hb)
{
    int b = blockIdx.x, t = threadIdx.x;
    for (int g = GG; g < GP; g++) {
        size_t o = ((size_t)b * GP + g) * EE + t;
        h[o] = 0.0f; hb[o] = 0;
    }
}

// --------- QKV GEMM: 128x128 tile, epilogue scatters Q/K rows + V^T ---------
__global__ __launch_bounds__(256) void qkv_gemm(
    const u16* __restrict__ hb, const u16* __restrict__ wqkvT,
    u16* __restrict__ qb, u16* __restrict__ kb, u16* __restrict__ vt)
{
    __shared__ __align__(16) u16 sA[128 * 64];
    __shared__ __align__(16) u16 sB[128 * 64];
    int tid = threadIdx.x, lane = tid & 63, w = tid >> 6;
    int wm = w >> 1, wn = w & 1;
    int lr = lane & 15, q = lane >> 4;
    int brow = blockIdx.x * 128;
    int bcol = blockIdx.y * 128;

    f32x4 acc[4][4];
    #pragma unroll
    for (int i = 0; i < 4; i++)
        #pragma unroll
        for (int j = 0; j < 4; j++) acc[i][j] = {0.0f, 0.0f, 0.0f, 0.0f};

    for (int ks = 0; ks < 4; ks++) {
        __syncthreads();
        stage_swz(hb + (size_t)brow * 256, 256, ks * 64, sA, 16, w, 4, lane);
        stage_swz(wqkvT + (size_t)bcol * 256, 256, ks * 64, sB, 16, w, 4, lane);
        __syncthreads();
        #pragma unroll
        for (int kk = 0; kk < 2; kk++) {
            bf16x8 a[4], b[4];
            #pragma unroll
            for (int i = 0; i < 4; i++) {
                a[i] = lds_frag(sA, wm * 64 + i * 16 + lr, kk, q);
                b[i] = lds_frag(sB, wn * 64 + i * 16 + lr, kk, q);
            }
            #pragma unroll
            for (int mi = 0; mi < 4; mi++)
                #pragma unroll
                for (int ni = 0; ni < 4; ni++)
                    acc[mi][ni] = MFMA(a[mi], b[ni], acc[mi][ni]);
        }
    }

    if (bcol < 512) {
        u16* dst = (bcol < 256) ? qb : kb;
        int cOff = bcol & 255;
        #pragma unroll
        for (int mi = 0; mi < 4; mi++)
            #pragma unroll
            for (int ni = 0; ni < 4; ni++) {
                int col = cOff + wn * 64 + ni * 16 + lr;
                #pragma unroll
                for (int j = 0; j < 4; j++) {
                    int rowG = brow + wm * 64 + mi * 16 + q * 4 + j;
                    dst[(size_t)rowG * 256 + col] = f2bf(acc[mi][ni][j]);
                }
            }
    } else {
        #pragma unroll
        for (int mi = 0; mi < 4; mi++) {
            int rowG0 = brow + wm * 64 + mi * 16 + q * 4;
            int b0 = rowG0 / GP;
            int g0 = rowG0 - b0 * GP;
            #pragma unroll
            for (int ni = 0; ni < 4; ni++) {
                int e = (bcol - 512) + wn * 64 + ni * 16 + lr;
                ushort4 u4;
                u4.x = f2bf(acc[mi][ni][0]);
                u4.y = f2bf(acc[mi][ni][1]);
                u4.z = f2bf(acc[mi][ni][2]);
                u4.w = f2bf(acc[mi][ni][3]);
                *(ushort4*)(vt + ((size_t)(b0 * EE + e)) * GP + g0) = u4;
            }
        }
    }
}

// --------- FF1 GEMM: 128x128 tile, epilogue bias+relu -> hidb bf16 ---------
__global__ __launch_bounds__(256) void ff1_gemm(
    const u16* __restrict__ hb, const u16* __restrict__ w1T,
    const float* __restrict__ bf1, u16* __restrict__ hidb)
{
    __shared__ __align__(16) u16 sA[128 * 64];
    __shared__ __align__(16) u16 sB[128 * 64];
    int tid = threadIdx.x, lane = tid & 63, w = tid >> 6;
    int wm = w >> 1, wn = w & 1;
    int lr = lane & 15, q = lane >> 4;
    int brow = blockIdx.x * 128;
    int bcol = blockIdx.y * 128;

    f32x4 acc[4][4];
    #pragma unroll
    for (int i = 0; i < 4; i++)
        #pragma unroll
        for (int j = 0; j < 4; j++) acc[i][j] = {0.0f, 0.0f, 0.0f, 0.0f};

    for (int ks = 0; ks < 4; ks++) {
        __syncthreads();
        stage_swz(hb + (size_t)brow * 256, 256, ks * 64, sA, 16, w, 4, lane);
        stage_swz(w1T + (size_t)bcol * 256, 256, ks * 64, sB, 16, w, 4, lane);
        __syncthreads();
        #pragma unroll
        for (int kk = 0; kk < 2; kk++) {
            bf16x8 a[4], b[4];
            #pragma unroll
            for (int i = 0; i < 4; i++) {
                a[i] = lds_frag(sA, wm * 64 + i * 16 + lr, kk, q);
                b[i] = lds_frag(sB, wn * 64 + i * 16 + lr, kk, q);
            }
            #pragma unroll
            for (int mi = 0; mi < 4; mi++)
                #pragma unroll
                for (int ni = 0; ni < 4; ni++)
                    acc[mi][ni] = MFMA(a[mi], b[ni], acc[mi][ni]);
        }
    }

    #pragma unroll
    for (int ni = 0; ni < 4; ni++) {
        int col = bcol + wn * 64 + ni * 16 + lr;
        float bias = bf1[col];
        #pragma unroll
        for (int mi = 0; mi < 4; mi++)
            #pragma unroll
            for (int j = 0; j < 4; j++) {
                int rowG = brow + wm * 64 + mi * 16 + q * 4 + j;
                float v = acc[mi][ni][j] + bias;
                hidb[(size_t)rowG * 512 + col] = f2bf(fmaxf(v, 0.0f));
            }
    }
}

// ---- GEMM + residual + LayerNorm: BM=128, BN=256(full row), 8 waves ----
template<int KSTEPS, int ASTR, int BSTR, bool HASB>
__global__ __launch_bounds__(512) void gemmln_kernel(
    const u16* __restrict__ A, const u16* __restrict__ Bw,
    const float* __restrict__ bias, float* __restrict__ h, u16* __restrict__ hb)
{
    __shared__ __align__(16) u16 sA[128 * 64];   // 16 KB
    __shared__ __align__(16) u16 sB[256 * 64];   // 32 KB
    int tid = threadIdx.x, lane = tid & 63, w = tid >> 6;
    int wm = w >> 2, wn = w & 3;
    int lr = lane & 15, q = lane >> 4;
    int brow = blockIdx.x * 128;

    f32x4 acc[4][4];
    #pragma unroll
    for (int i = 0; i < 4; i++)
        #pragma unroll
        for (int j = 0; j < 4; j++) acc[i][j] = {0.0f, 0.0f, 0.0f, 0.0f};

    for (int ks = 0; ks < KSTEPS; ks++) {
        __syncthreads();
        stage_swz(A + (size_t)brow * ASTR, ASTR, ks * 64, sA, 16, w, 8, lane);
        stage_swz(Bw, BSTR, ks * 64, sB, 32, w, 8, lane);
        __syncthreads();
        #pragma unroll
        for (int kk = 0; kk < 2; kk++) {
            bf16x8 a[4], b[4];
            #pragma unroll
            for (int i = 0; i < 4; i++) {
                a[i] = lds_frag(sA, wm * 64 + i * 16 + lr, kk, q);
                b[i] = lds_frag(sB, wn * 64 + i * 16 + lr, kk, q);
            }
            #pragma unroll
            for (int mi = 0; mi < 4; mi++)
                #pragma unroll
                for (int ni = 0; ni < 4; ni++)
                    acc[mi][ni] = MFMA(a[mi], b[ni], acc[mi][ni]);
        }
    }

    __syncthreads();
    float* sPart = (float*)sA;           // [4 wn][128 row][2]

    #pragma unroll
    for (int ni = 0; ni < 4; ni++) {
        int col = wn * 64 + ni * 16 + lr;
        float bv = HASB ? bias[col] : 0.0f;
        #pragma unroll
        for (int mi = 0; mi < 4; mi++)
            #pragma unroll
            for (int j = 0; j < 4; j++) {
                int rowG = brow + wm * 64 + mi * 16 + q * 4 + j;
                acc[mi][ni][j] += bv + h[(size_t)rowG * 256 + col];
            }
    }
    #pragma unroll
    for (int mi = 0; mi < 4; mi++)
        #pragma unroll
        for (int j = 0; j < 4; j++) {
            float s1 = 0.0f, s2 = 0.0f;
            #pragma unroll
            for (int ni = 0; ni < 4; ni++) {
                float v = acc[mi][ni][j];
                s1 += v; s2 += v * v;
            }
            s1 += __shfl_xor(s1, 1); s2 += __shfl_xor(s2, 1);
            s1 += __shfl_xor(s1, 2); s2 += __shfl_xor(s2, 2);
            s1 += __shfl_xor(s1, 4); s2 += __shfl_xor(s2, 4);
            s1 += __shfl_xor(s1, 8); s2 += __shfl_xor(s2, 8);
            if (lr == 0) {
                int lrow = wm * 64 + mi * 16 + q * 4 + j;
                sPart[(wn * 128 + lrow) * 2 + 0] = s1;
                sPart[(wn * 128 + lrow) * 2 + 1] = s2;
            }
        }
    __syncthreads();

    #pragma unroll
    for (int mi = 0; mi < 4; mi++)
        #pragma unroll
        for (int j = 0; j < 4; j++) {
            int lrow = wm * 64 + mi * 16 + q * 4 + j;
            float s1 = sPart[lrow * 2] + sPart[(128 + lrow) * 2] +
                       sPart[(256 + lrow) * 2] + sPart[(384 + lrow) * 2];
            float s2 = sPart[lrow * 2 + 1] + sPart[(128 + lrow) * 2 + 1] +
                       sPart[(256 + lrow) * 2 + 1] + sPart[(384 + lrow) * 2 + 1];
            float mean = s1 * (1.0f / 256.0f);
            float var  = s2 * (1.0f / 256.0f) - mean * mean;
            float rstd = rsqrtf(var + 1e-5f);
            int rowG = brow + lrow;
            #pragma unroll
            for (int ni = 0; ni < 4; ni++) {
                int col = wn * 64 + ni * 16 + lr;
                float v = (acc[mi][ni][j] - mean) * rstd;
                size_t o = (size_t)rowG * 256 + col;
                h[o] = v; hb[o] = f2bf(v);
            }
        }
}

// ------- attention core: S=QK^T, softmax(in-reg), PV -> aob -------
// 32 q-rows/block, 8 waves (wave = 16 rows x 80 j), XCD-bijective swizzle.
// Small blocks keep the in-flight batch working set per XCD (~9.6 batches x
// 320 KB K/V ~ 3.1 MB) inside the 4 MB XCD L2 -> K/V loads are L2 hits.
// launch_bounds(512,6): VGPR<=85 -> 24 waves/CU for TLP latency hiding.
// NOTE: aob may alias qb (qb reads before P barriers; aob writes after;
// each block only touches its own 32 rows of both).
__global__ __launch_bounds__(512, 6) void attn_core(
    const u16* __restrict__ qb, const u16* __restrict__ kb,
    const u16* __restrict__ vt, const float* __restrict__ obs,
    u16* __restrict__ aob)
{
    __shared__ __align__(16) u16 sP[32][328];   // 20,992 B
    __shared__ float sBias[320];
    __shared__ float sPm[4][32], sPs[4][32];

    int id = blockIdx.x;                 // 2560 blocks
    int xcd = id & 7, jj = id >> 3;      // jj in [0,320)
    int tile = jj % 10, bgrp = jj / 10;  // bgrp in [0,32)
    int b = xcd + 8 * bgrp;              // bijective batch
    int t0 = tile * 32;

    int tid = threadIdx.x, w = tid >> 6, lane = tid & 63;
    int mh = w >> 2, jq = w & 3;         // row-half (16), j-quarter (80)
    int lr = lane & 15, q = lane >> 4, lk = q * 8;

    if (tid < 320) {
        float msk = (tid < GG) ? obs[((size_t)b * GG + tid) * 9 + 8] : 0.0f;
        sBias[tid] = (1.0f - msk) * -1e9f;
    }
    __syncthreads();

    const u16* qbase = qb + ((size_t)(b * GP + t0 + mh * 16)) * 256;
    const u16* kbase = kb + ((size_t)b * GP) * 256;

    // scores: rows [mh*16,+16) x j in [jq*80,+80)
    f32x4 sacc[5];
    #pragma unroll
    for (int jt = 0; jt < 5; jt++) sacc[jt] = {0.0f, 0.0f, 0.0f, 0.0f};

    #pragma unroll
    for (int k = 0; k < 8; k++) {
        bf16x8 a0 = *(const bf16x8*)(qbase + (size_t)lr * 256 + k * 32 + lk);
        #pragma unroll
        for (int jt = 0; jt < 5; jt++) {
            bf16x8 bb = *(const bf16x8*)(kbase + ((size_t)(jq * 80 + jt * 16 + lr)) * 256 + k * 32 + lk);
            sacc[jt] = MFMA(a0, bb, sacc[jt]);
        }
    }

    #pragma unroll
    for (int jt = 0; jt < 5; jt++) {
        float bia = sBias[jq * 80 + jt * 16 + lr];
        #pragma unroll
        for (int r = 0; r < 4; r++)
            sacc[jt][r] = sacc[jt][r] * 0.0625f + bia;
    }
    // partial row max over this wave's j range
    #pragma unroll
    for (int r = 0; r < 4; r++) {
        float mx = -1e30f;
        #pragma unroll
        for (int jt = 0; jt < 5; jt++) mx = fmaxf(mx, sacc[jt][r]);
        mx = fmaxf(mx, __shfl_xor(mx, 1));
        mx = fmaxf(mx, __shfl_xor(mx, 2));
        mx = fmaxf(mx, __shfl_xor(mx, 4));
        mx = fmaxf(mx, __shfl_xor(mx, 8));
        if (lr == 0) sPm[jq][mh * 16 + q * 4 + r] = mx;
    }
    __syncthreads();
    #pragma unroll
    for (int r = 0; r < 4; r++) {
        int row = mh * 16 + q * 4 + r;
        float rm = fmaxf(fmaxf(sPm[0][row], sPm[1][row]), fmaxf(sPm[2][row], sPm[3][row]));
        float ss = 0.0f;
        #pragma unroll
        for (int jt = 0; jt < 5; jt++) {
            float e = __expf(sacc[jt][r] - rm);
            sacc[jt][r] = e;
            ss += e;
        }
        ss += __shfl_xor(ss, 1);
        ss += __shfl_xor(ss, 2);
        ss += __shfl_xor(ss, 4);
        ss += __shfl_xor(ss, 8);
        if (lr == 0) sPs[jq][row] = ss;
    }
    __syncthreads();
    #pragma unroll
    for (int r = 0; r < 4; r++) {
        int row = mh * 16 + q * 4 + r;
        float inv = 1.0f / (sPs[0][row] + sPs[1][row] + sPs[2][row] + sPs[3][row]);
        #pragma unroll
        for (int jt = 0; jt < 5; jt++)
            sP[row][jq * 80 + jt * 16 + lr] = f2bf(sacc[jt][r] * inv);
    }
    __syncthreads();

    // PV: rows [mh*16,+16) x e in [jq*64,+64), 1-deep V prefetch
    const u16* vbase = vt + (size_t)b * EE * GP;
    f32x4 oacc[4];
    #pragma unroll
    for (int ni = 0; ni < 4; ni++) oacc[ni] = {0.0f, 0.0f, 0.0f, 0.0f};

    bf16x8 vc[4], vn[4];
    #pragma unroll
    for (int ni = 0; ni < 4; ni++)
        vc[ni] = *(const bf16x8*)(vbase + ((size_t)(jq * 64 + ni * 16 + lr)) * GP + lk);

    #pragma unroll
    for (int ks = 0; ks < 10; ks++) {
        if (ks < 9) {
            #pragma unroll
            for (int ni = 0; ni < 4; ni++)
                vn[ni] = *(const bf16x8*)(vbase + ((size_t)(jq * 64 + ni * 16 + lr)) * GP + (ks + 1) * 32 + lk);
        }
        bf16x8 a0 = *(const bf16x8*)(&sP[mh * 16 + lr][ks * 32 + lk]);
        #pragma unroll
        for (int ni = 0; ni < 4; ni++)
            oacc[ni] = MFMA(a0, vc[ni], oacc[ni]);
        #pragma unroll
        for (int ni = 0; ni < 4; ni++) vc[ni] = vn[ni];
    }
    #pragma unroll
    for (int ni = 0; ni < 4; ni++) {
        int col = jq * 64 + ni * 16 + lr;
        #pragma unroll
        for (int r = 0; r < 4; r++) {
            int row = mh * 16 + q * 4 + r;
            aob[((size_t)(b * GP + t0 + row)) * 256 + col] = f2bf(oacc[ni][r]);
        }
    }
}

// ------------- head part 1: graph embed -> fixed context -> u[b] -------------
__global__ __launch_bounds__(256) void final1_kernel(
    const float* __restrict__ h, const float* __restrict__ obs,
    const float* __restrict__ w_fc, const float* __restrict__ w_pn,
    float* __restrict__ u)
{
    int b = blockIdx.x;
    int t = threadIdx.x;
    __shared__ float ges[EE];
    __shared__ float fcs[EE];

    float acc = 0.0f, vlen = 0.0f;
    for (int g = 0; g < GG; g++) {
        float m = obs[((size_t)b * GG + g) * 9 + 8];
        vlen += m;
        acc += h[((size_t)b * GP + g) * EE + t] * m;
    }
    ges[t] = acc / vlen;
    __syncthreads();

    float fc = 0.0f;
    for (int kk = 0; kk < EE; kk++) fc += ges[kk] * w_fc[kk * EE + t];
    fcs[t] = fc;
    __syncthreads();

    const float4* wp = reinterpret_cast<const float4*>(w_pn + (size_t)t * 3 * EE);
    float ua = 0.0f;
    for (int kk = 0; kk < EE / 4; kk++) {
        float4 w = wp[kk];
        ua += w.x * fcs[kk * 4] + w.y * fcs[kk * 4 + 1] +
              w.z * fcs[kk * 4 + 2] + w.w * fcs[kk * 4 + 3];
    }
    u[(size_t)b * EE + t] = ua;
}

// ------------- head part 2: compat -> tanh clip -> masked softmax -------------
__global__ __launch_bounds__(128) void final2_kernel(
    const float* __restrict__ h, const float* __restrict__ obs,
    const float* __restrict__ u, float* __restrict__ out)
{
    int b = blockIdx.x;
    int t = threadIdx.x;
    __shared__ float us[EE];
    __shared__ float red[8];
    us[t]       = u[(size_t)b * EE + t];
    us[t + 128] = u[(size_t)b * EE + t + 128];
    __syncthreads();

    float logit = -INFINITY;
    float m = 0.0f;
    if (t < LHN) {
        int g = IHN + t;
        m = obs[((size_t)b * GG + g) * 9 + 8];
        const float4* hr = reinterpret_cast<const float4*>(h + ((size_t)b * GP + g) * EE);
        float c = 0.0f;
        for (int kk = 0; kk < EE / 4; kk++) {
            float4 hv = hr[kk];
            c += hv.x * us[kk * 4] + hv.y * us[kk * 4 + 1] +
                 hv.z * us[kk * 4 + 2] + hv.w * us[kk * 4 + 3];
        }
        c *= m;
        c *= 0.0625f;
        logit = tanhf(c) * 10.0f;
    }
    float bm = blockReduceMax(logit, red);
    float e  = (t < LHN) ? __expf(logit - bm) : 0.0f;
    float bs = blockReduceSum(e, red);
    float p  = e / bs;
    float masked = (t < LHN) ? (p * m + 1e-20f) : 0.0f;
    float bs2 = blockReduceSum(masked, red);
    if (t < LHN) out[(size_t)b * LHN + t] = masked / bs2;
}

extern "C" void kernel_launch(void* const* d_in, const int* in_sizes, int n_in,
                              void* d_out, int out_size, void* d_ws, size_t ws_size,
                              hipStream_t stream) {
    const float* obs   = (const float*)d_in[0];
    const float* wi1   = (const float*)d_in[1];
    const float* bi1   = (const float*)d_in[2];
    const float* wi2   = (const float*)d_in[3];
    const float* bi2   = (const float*)d_in[4];
    const float* wl1   = (const float*)d_in[5];
    const float* bl1   = (const float*)d_in[6];
    const float* wl2   = (const float*)d_in[7];
    const float* bl2   = (const float*)d_in[8];
    const float* wn1   = (const float*)d_in[9];
    const float* bn1   = (const float*)d_in[10];
    const float* wn2   = (const float*)d_in[11];
    const float* bn2   = (const float*)d_in[12];
    const float* e_wq  = (const float*)d_in[13];
    const float* e_wk  = (const float*)d_in[14];
    const float* e_wv  = (const float*)d_in[15];
    const float* e_wo  = (const float*)d_in[16];
    const float* e_wf1 = (const float*)d_in[17];
    const float* e_bf1 = (const float*)d_in[18];
    const float* e_wf2 = (const float*)d_in[19];
    const float* e_bf2 = (const float*)d_in[20];
    const float* w_pn  = (const float*)d_in[21];
    const float* w_fc  = (const float*)d_in[22];
    float* outp = (float*)d_out;

    // ---- compact workspace layout: 254,017,536 B total ----
    char* wsc = (char*)d_ws;
    float* h    = (float*)wsc;
    u16*   hb   = (u16*)(wsc + 83886080);
    u16*   qaob = (u16*)(wsc + 125829120);   // qb, later aob
    u16*   kb   = (u16*)(wsc + 167772160);
    u16*   vt   = (u16*)(wsc + 209715200);
    u16*   wT   = (u16*)(wsc + 251658240);
    float* ubuf = (float*)(wsc + 253755392);
    u16*   hidb = kb;  // overlays kb+vt (disjoint lifetime)

    prep_kernel<<<dim3(512, 12), 256, 0, stream>>>(e_wq, e_wk, e_wv, e_wo, e_wf1, e_wf2, wT);
    pad_kernel<<<BB, 256, 0, stream>>>(h, hb);
    embed_seg<ILN, IHN, 0><<<IHN * BB / 32, 256, 0, stream>>>(obs, wi1, bi1, wi2, bi2, h, hb);
    embed_seg<8, LHN, IHN><<<LHN * BB / 32, 256, 0, stream>>>(obs, wl1, bl1, wl2, bl2, h, hb);
    embed_seg<6, 1, IHN + LHN><<<BB / 32, 256, 0, stream>>>(obs, wn1, bn1, wn2, bn2, h, hb);

    const size_t WL = 524288;
    for (int l = 0; l < NL; l++) {
        u16* wqkvT = wT + l * WL;
        u16* woT   = wqkvT + 196608;
        u16* w1T   = wqkvT + 262144;
        u16* w2T   = wqkvT + 393216;
        const float* bf1 = e_bf1 + (size_t)l * FFH;
        const float* bf2 = e_bf2 + (size_t)l * EE;

        qkv_gemm<<<dim3(MT / 128, 6), 256, 0, stream>>>(hb, wqkvT, qaob, kb, vt);
        attn_core<<<2560, 512, 0, stream>>>(qaob, kb, vt, obs, qaob);
        gemmln_kernel<4, 256, 256, false><<<MT / 128, 512, 0, stream>>>(qaob, woT, nullptr, h, hb);
        ff1_gemm<<<dim3(MT / 128, 4), 256, 0, stream>>>(hb, w1T, bf1, hidb);
        gemmln_kernel<8, 512, 512, true><<<MT / 128, 512, 0, stream>>>(hidb, w2T, bf2, h, hb);
    }
    final1_kernel<<<BB, 256, 0, stream>>>(h, obs, w_fc, w_pn, ubuf);
    final2_kernel<<<BB, 128, 0, stream>>>(h, obs, ubuf, outp);
}

// Round 8
// 902.419 us; speedup vs baseline: 1.1334x; 1.1334x over previous
//
#include <hip/hip_runtime.h>
#include <math.h>

static constexpr int BB   = 256;   // batch
static constexpr int IHN  = 200;   // internal tokens
static constexpr int ILN  = 6;     // internal feature dim
static constexpr int LHN  = 100;   // leaf tokens
static constexpr int EE   = 256;   // embed dim
static constexpr int FFH  = 512;   // ff hidden
static constexpr int NL   = 2;     // layers
static constexpr int GG   = 301;   // real tokens
static constexpr int GP   = 320;   // padded tokens (10 x 32)
static constexpr int MT   = BB * GP;  // 81920 total token rows (640 x 128)

typedef unsigned short u16;
typedef short bf16x8 __attribute__((ext_vector_type(8)));
typedef float f32x4 __attribute__((ext_vector_type(4)));

#define MFMA(a, b, c) __builtin_amdgcn_mfma_f32_16x16x32_bf16((a), (b), (c), 0, 0, 0)

__device__ __forceinline__ u16 f2bf(float f) {
    union { float f; unsigned u; } v; v.f = f;
    unsigned r = v.u + 0x7FFFu + ((v.u >> 16) & 1u);
    return (u16)(r >> 16);
}

// ---------------- wave/block reduction helpers (wave = 64) ----------------
__device__ __forceinline__ float waveReduceSum(float v) {
    for (int o = 32; o > 0; o >>= 1) v += __shfl_down(v, o, 64);
    return v;
}
__device__ __forceinline__ float waveReduceMax(float v) {
    for (int o = 32; o > 0; o >>= 1) v = fmaxf(v, __shfl_down(v, o, 64));
    return v;
}
__device__ __forceinline__ float blockReduceSum(float v, float* red) {
    int lane = threadIdx.x & 63;
    int w    = threadIdx.x >> 6;
    int nw   = (blockDim.x + 63) >> 6;
    v = waveReduceSum(v);
    if (lane == 0) red[w] = v;
    __syncthreads();
    if (threadIdx.x < 64) {
        float x = (lane < nw) ? red[lane] : 0.0f;
        x = waveReduceSum(x);
        if (lane == 0) red[0] = x;
    }
    __syncthreads();
    float r = red[0];
    __syncthreads();
    return r;
}
__device__ __forceinline__ float blockReduceMax(float v, float* red) {
    int lane = threadIdx.x & 63;
    int w    = threadIdx.x >> 6;
    int nw   = (blockDim.x + 63) >> 6;
    v = waveReduceMax(v);
    if (lane == 0) red[w] = v;
    __syncthreads();
    if (threadIdx.x < 64) {
        float x = (lane < nw) ? red[lane] : -INFINITY;
        x = waveReduceMax(x);
        if (lane == 0) red[0] = x;
    }
    __syncthreads();
    float r = red[0];
    __syncthreads();
    return r;
}

// --------- staging: global -> LDS tile [rows][64] bf16, XOR-swizzled ---------
__device__ __forceinline__ void stage_swz(const u16* src, int strideShorts, int k0,
                                          u16* ldsTile, int nChunks, int wave,
                                          int nWaves, int lane)
{
    for (int c = wave; c < nChunks; c += nWaves) {
        int o = c * 1024 + lane * 16;
        int row = o >> 7;
        int cb = (o & 127) ^ ((row & 7) << 4);
        const u16* g = src + (size_t)row * strideShorts + k0 + (cb >> 1);
        __builtin_amdgcn_global_load_lds(
            (const __attribute__((address_space(1))) unsigned int*)g,
            (__attribute__((address_space(3))) unsigned int*)((char*)ldsTile + c * 1024),
            16, 0, 0);
    }
}

__device__ __forceinline__ bf16x8 lds_frag(const u16* tile, int row, int kk, int q)
{
    int cb = (kk * 64 + q * 16) ^ ((row & 7) << 4);
    return *(const bf16x8*)((const char*)tile + row * 128 + cb);
}

// ------------- prep: transpose encoder weights to bf16 [N][K] -------------
__global__ __launch_bounds__(256) void prep_kernel(
    const float* __restrict__ wq, const float* __restrict__ wk,
    const float* __restrict__ wv, const float* __restrict__ wo,
    const float* __restrict__ wf1, const float* __restrict__ wf2,
    u16* __restrict__ wT)
{
    int l = blockIdx.y / 6, m = blockIdx.y % 6;
    int idx = blockIdx.x * 256 + threadIdx.x;
    u16* dst = wT + (size_t)l * 524288;
    if (m < 4) {
        if (idx >= EE * EE) return;
        const float* src = (m == 0 ? wq : m == 1 ? wk : m == 2 ? wv : wo) + (size_t)l * EE * EE;
        int r = idx >> 8, c = idx & 255;
        dst[m * 65536 + idx] = f2bf(src[(size_t)c * EE + r]);
    } else if (m == 4) {
        if (idx >= FFH * EE) return;
        const float* src = wf1 + (size_t)l * EE * FFH;
        int r = idx >> 8, c = idx & 255;
        dst[262144 + idx] = f2bf(src[(size_t)c * FFH + r]);
    } else {
        if (idx >= EE * FFH) return;
        const float* src = wf2 + (size_t)l * FFH * EE;
        int r = idx >> 9, c = idx & 511;
        dst[393216 + idx] = f2bf(src[(size_t)c * EE + r]);
    }
}

// ---------- embed (segment version): 32 tokens/block, w2 col in regs ----------
template<int IND, int SEG, int G0>
__global__ __launch_bounds__(256) void embed_seg(
    const float* __restrict__ obs,
    const float* __restrict__ w1, const float* __restrict__ b1,
    const float* __restrict__ w2, const float* __restrict__ b2,
    float* __restrict__ h, u16* __restrict__ hb)
{
    __shared__ float xs[32][9];
    __shared__ float hid[32][33];
    int t = threadIdx.x;
    int fi0 = blockIdx.x * 32;

    for (int p = t; p < 32 * 9; p += 256) {
        int tok = p / 9, f = p % 9;
        int fi = fi0 + tok;
        int b = fi / SEG, g = G0 + fi % SEG;
        xs[tok][f] = obs[((size_t)b * GG + g) * 9 + f];
    }
    __syncthreads();

    #pragma unroll
    for (int p = 0; p < 4; p++) {
        int idx = p * 256 + t;
        int tok = idx >> 5, hcol = idx & 31;
        float a = b1[hcol];
        #pragma unroll
        for (int i = 0; i < IND; i++) a += xs[tok][i] * w1[i * 32 + hcol];
        hid[tok][hcol] = (a > 0.0f) ? a : 0.01f * a;
    }
    __syncthreads();

    float w2c[32];
    #pragma unroll
    for (int j = 0; j < 32; j++) w2c[j] = w2[j * EE + t];
    float bb = b2[t];
    for (int tok = 0; tok < 32; tok++) {
        int fi = fi0 + tok;
        int b = fi / SEG, g = G0 + fi % SEG;
        float a = bb;
        #pragma unroll
        for (int j = 0; j < 32; j++) a += hid[tok][j] * w2c[j];
        size_t o = ((size_t)b * GP + g) * EE + t;
        h[o] = a; hb[o] = f2bf(a);
    }
}

// zero the pad rows g in [GG, GP)
__global__ __launch_bounds__(256) void pad_kernel(float* __restrict__ h, u16* __restrict__ hb)
{
    int b = blockIdx.x, t = threadIdx.x;
    for (int g = GG; g < GP; g++) {
        size_t o = ((size_t)b * GP + g) * EE + t;
        h[o] = 0.0f; hb[o] = 0;
    }
}

// --------- QKV GEMM: 128x128 tile, epilogue scatters Q/K rows + V^T ---------
__global__ __launch_bounds__(256) void qkv_gemm(
    const u16* __restrict__ hb, const u16* __restrict__ wqkvT,
    u16* __restrict__ qb, u16* __restrict__ kb, u16* __restrict__ vt)
{
    __shared__ __align__(16) u16 sA[128 * 64];
    __shared__ __align__(16) u16 sB[128 * 64];
    int tid = threadIdx.x, lane = tid & 63, w = tid >> 6;
    int wm = w >> 1, wn = w & 1;
    int lr = lane & 15, q = lane >> 4;
    int brow = blockIdx.x * 128;
    int bcol = blockIdx.y * 128;

    f32x4 acc[4][4];
    #pragma unroll
    for (int i = 0; i < 4; i++)
        #pragma unroll
        for (int j = 0; j < 4; j++) acc[i][j] = {0.0f, 0.0f, 0.0f, 0.0f};

    for (int ks = 0; ks < 4; ks++) {
        __syncthreads();
        stage_swz(hb + (size_t)brow * 256, 256, ks * 64, sA, 16, w, 4, lane);
        stage_swz(wqkvT + (size_t)bcol * 256, 256, ks * 64, sB, 16, w, 4, lane);
        __syncthreads();
        #pragma unroll
        for (int kk = 0; kk < 2; kk++) {
            bf16x8 a[4], b[4];
            #pragma unroll
            for (int i = 0; i < 4; i++) {
                a[i] = lds_frag(sA, wm * 64 + i * 16 + lr, kk, q);
                b[i] = lds_frag(sB, wn * 64 + i * 16 + lr, kk, q);
            }
            #pragma unroll
            for (int mi = 0; mi < 4; mi++)
                #pragma unroll
                for (int ni = 0; ni < 4; ni++)
                    acc[mi][ni] = MFMA(a[mi], b[ni], acc[mi][ni]);
        }
    }

    if (bcol < 512) {
        u16* dst = (bcol < 256) ? qb : kb;
        int cOff = bcol & 255;
        #pragma unroll
        for (int mi = 0; mi < 4; mi++)
            #pragma unroll
            for (int ni = 0; ni < 4; ni++) {
                int col = cOff + wn * 64 + ni * 16 + lr;
                #pragma unroll
                for (int j = 0; j < 4; j++) {
                    int rowG = brow + wm * 64 + mi * 16 + q * 4 + j;
                    dst[(size_t)rowG * 256 + col] = f2bf(acc[mi][ni][j]);
                }
            }
    } else {
        #pragma unroll
        for (int mi = 0; mi < 4; mi++) {
            int rowG0 = brow + wm * 64 + mi * 16 + q * 4;
            int b0 = rowG0 / GP;
            int g0 = rowG0 - b0 * GP;
            #pragma unroll
            for (int ni = 0; ni < 4; ni++) {
                int e = (bcol - 512) + wn * 64 + ni * 16 + lr;
                ushort4 u4;
                u4.x = f2bf(acc[mi][ni][0]);
                u4.y = f2bf(acc[mi][ni][1]);
                u4.z = f2bf(acc[mi][ni][2]);
                u4.w = f2bf(acc[mi][ni][3]);
                *(ushort4*)(vt + ((size_t)(b0 * EE + e)) * GP + g0) = u4;
            }
        }
    }
}

// --------- FF1 GEMM: 128x128 tile, epilogue bias+relu -> hidb bf16 ---------
__global__ __launch_bounds__(256) void ff1_gemm(
    const u16* __restrict__ hb, const u16* __restrict__ w1T,
    const float* __restrict__ bf1, u16* __restrict__ hidb)
{
    __shared__ __align__(16) u16 sA[128 * 64];
    __shared__ __align__(16) u16 sB[128 * 64];
    int tid = threadIdx.x, lane = tid & 63, w = tid >> 6;
    int wm = w >> 1, wn = w & 1;
    int lr = lane & 15, q = lane >> 4;
    int brow = blockIdx.x * 128;
    int bcol = blockIdx.y * 128;

    f32x4 acc[4][4];
    #pragma unroll
    for (int i = 0; i < 4; i++)
        #pragma unroll
        for (int j = 0; j < 4; j++) acc[i][j] = {0.0f, 0.0f, 0.0f, 0.0f};

    for (int ks = 0; ks < 4; ks++) {
        __syncthreads();
        stage_swz(hb + (size_t)brow * 256, 256, ks * 64, sA, 16, w, 4, lane);
        stage_swz(w1T + (size_t)bcol * 256, 256, ks * 64, sB, 16, w, 4, lane);
        __syncthreads();
        #pragma unroll
        for (int kk = 0; kk < 2; kk++) {
            bf16x8 a[4], b[4];
            #pragma unroll
            for (int i = 0; i < 4; i++) {
                a[i] = lds_frag(sA, wm * 64 + i * 16 + lr, kk, q);
                b[i] = lds_frag(sB, wn * 64 + i * 16 + lr, kk, q);
            }
            #pragma unroll
            for (int mi = 0; mi < 4; mi++)
                #pragma unroll
                for (int ni = 0; ni < 4; ni++)
                    acc[mi][ni] = MFMA(a[mi], b[ni], acc[mi][ni]);
        }
    }

    #pragma unroll
    for (int ni = 0; ni < 4; ni++) {
        int col = bcol + wn * 64 + ni * 16 + lr;
        float bias = bf1[col];
        #pragma unroll
        for (int mi = 0; mi < 4; mi++)
            #pragma unroll
            for (int j = 0; j < 4; j++) {
                int rowG = brow + wm * 64 + mi * 16 + q * 4 + j;
                float v = acc[mi][ni][j] + bias;
                hidb[(size_t)rowG * 512 + col] = f2bf(fmaxf(v, 0.0f));
            }
    }
}

// ---- GEMM + residual + LayerNorm: BM=128, BN=256(full row), 8 waves ----
template<int KSTEPS, int ASTR, int BSTR, bool HASB>
__global__ __launch_bounds__(512) void gemmln_kernel(
    const u16* __restrict__ A, const u16* __restrict__ Bw,
    const float* __restrict__ bias, float* __restrict__ h, u16* __restrict__ hb)
{
    __shared__ __align__(16) u16 sA[128 * 64];   // 16 KB
    __shared__ __align__(16) u16 sB[256 * 64];   // 32 KB
    int tid = threadIdx.x, lane = tid & 63, w = tid >> 6;
    int wm = w >> 2, wn = w & 3;
    int lr = lane & 15, q = lane >> 4;
    int brow = blockIdx.x * 128;

    f32x4 acc[4][4];
    #pragma unroll
    for (int i = 0; i < 4; i++)
        #pragma unroll
        for (int j = 0; j < 4; j++) acc[i][j] = {0.0f, 0.0f, 0.0f, 0.0f};

    for (int ks = 0; ks < KSTEPS; ks++) {
        __syncthreads();
        stage_swz(A + (size_t)brow * ASTR, ASTR, ks * 64, sA, 16, w, 8, lane);
        stage_swz(Bw, BSTR, ks * 64, sB, 32, w, 8, lane);
        __syncthreads();
        #pragma unroll
        for (int kk = 0; kk < 2; kk++) {
            bf16x8 a[4], b[4];
            #pragma unroll
            for (int i = 0; i < 4; i++) {
                a[i] = lds_frag(sA, wm * 64 + i * 16 + lr, kk, q);
                b[i] = lds_frag(sB, wn * 64 + i * 16 + lr, kk, q);
            }
            #pragma unroll
            for (int mi = 0; mi < 4; mi++)
                #pragma unroll
                for (int ni = 0; ni < 4; ni++)
                    acc[mi][ni] = MFMA(a[mi], b[ni], acc[mi][ni]);
        }
    }

    __syncthreads();
    float* sPart = (float*)sA;           // [4 wn][128 row][2]

    #pragma unroll
    for (int ni = 0; ni < 4; ni++) {
        int col = wn * 64 + ni * 16 + lr;
        float bv = HASB ? bias[col] : 0.0f;
        #pragma unroll
        for (int mi = 0; mi < 4; mi++)
            #pragma unroll
            for (int j = 0; j < 4; j++) {
                int rowG = brow + wm * 64 + mi * 16 + q * 4 + j;
                acc[mi][ni][j] += bv + h[(size_t)rowG * 256 + col];
            }
    }
    #pragma unroll
    for (int mi = 0; mi < 4; mi++)
        #pragma unroll
        for (int j = 0; j < 4; j++) {
            float s1 = 0.0f, s2 = 0.0f;
            #pragma unroll
            for (int ni = 0; ni < 4; ni++) {
                float v = acc[mi][ni][j];
                s1 += v; s2 += v * v;
            }
            s1 += __shfl_xor(s1, 1); s2 += __shfl_xor(s2, 1);
            s1 += __shfl_xor(s1, 2); s2 += __shfl_xor(s2, 2);
            s1 += __shfl_xor(s1, 4); s2 += __shfl_xor(s2, 4);
            s1 += __shfl_xor(s1, 8); s2 += __shfl_xor(s2, 8);
            if (lr == 0) {
                int lrow = wm * 64 + mi * 16 + q * 4 + j;
                sPart[(wn * 128 + lrow) * 2 + 0] = s1;
                sPart[(wn * 128 + lrow) * 2 + 1] = s2;
            }
        }
    __syncthreads();

    #pragma unroll
    for (int mi = 0; mi < 4; mi++)
        #pragma unroll
        for (int j = 0; j < 4; j++) {
            int lrow = wm * 64 + mi * 16 + q * 4 + j;
            float s1 = sPart[lrow * 2] + sPart[(128 + lrow) * 2] +
                       sPart[(256 + lrow) * 2] + sPart[(384 + lrow) * 2];
            float s2 = sPart[lrow * 2 + 1] + sPart[(128 + lrow) * 2 + 1] +
                       sPart[(256 + lrow) * 2 + 1] + sPart[(384 + lrow) * 2 + 1];
            float mean = s1 * (1.0f / 256.0f);
            float var  = s2 * (1.0f / 256.0f) - mean * mean;
            float rstd = rsqrtf(var + 1e-5f);
            int rowG = brow + lrow;
            #pragma unroll
            for (int ni = 0; ni < 4; ni++) {
                int col = wn * 64 + ni * 16 + lr;
                float v = (acc[mi][ni][j] - mean) * rstd;
                size_t o = (size_t)rowG * 256 + col;
                h[o] = v; hb[o] = f2bf(v);
            }
        }
}

// ------- attention core: S=QK^T, softmax(in-reg), PV -> aob -------
// 32 q-rows/block, 4 waves (256 thr). Each wave computes ALL 32 rows x its
// own j-quarter (80 keys) -> K and V each read ONCE per block from L2
// (no cross-wave duplication); Q dup 4x (cheap, 65 KB). LDS ~23 KB ->
// 6 blocks/CU by LDS; natural VGPR ~90-110 (no launch cap -> no spills).
// XCD-bijective swizzle keeps a batch's K/V on one XCD's L2.
// NOTE: aob may alias qb (qb reads before P barriers; aob writes after;
// each block only touches its own 32 rows of both).
__global__ __launch_bounds__(256) void attn_core(
    const u16* __restrict__ qb, const u16* __restrict__ kb,
    const u16* __restrict__ vt, const float* __restrict__ obs,
    u16* __restrict__ aob)
{
    __shared__ __align__(16) u16 sP[32][328];   // 20,992 B
    __shared__ float sBias[320];
    __shared__ float sPm[4][32], sPs[4][32];

    int id = blockIdx.x;                 // 2560 blocks
    int xcd = id & 7, jj = id >> 3;      // jj in [0,320)
    int tile = jj % 10, bgrp = jj / 10;  // bgrp in [0,32)
    int b = xcd + 8 * bgrp;              // bijective batch
    int t0 = tile * 32;

    int tid = threadIdx.x, jq = tid >> 6, lane = tid & 63;
    int lr = lane & 15, q = lane >> 4, lk = q * 8;

    for (int j = tid; j < 320; j += 256) {
        float msk = (j < GG) ? obs[((size_t)b * GG + j) * 9 + 8] : 0.0f;
        sBias[j] = (1.0f - msk) * -1e9f;
    }
    __syncthreads();

    const u16* qbase = qb + ((size_t)(b * GP + t0)) * 256;
    const u16* kbase = kb + ((size_t)b * GP) * 256;

    // scores: all 32 rows (2 row-tiles) x j in [jq*80, +80)
    f32x4 sacc[2][5];
    #pragma unroll
    for (int mi = 0; mi < 2; mi++)
        #pragma unroll
        for (int jt = 0; jt < 5; jt++) sacc[mi][jt] = {0.0f, 0.0f, 0.0f, 0.0f};

    #pragma unroll
    for (int k = 0; k < 8; k++) {
        bf16x8 a0 = *(const bf16x8*)(qbase + (size_t)lr * 256 + k * 32 + lk);
        bf16x8 a1 = *(const bf16x8*)(qbase + (size_t)(16 + lr) * 256 + k * 32 + lk);
        #pragma unroll
        for (int jt = 0; jt < 5; jt++) {
            bf16x8 bb = *(const bf16x8*)(kbase + ((size_t)(jq * 80 + jt * 16 + lr)) * 256 + k * 32 + lk);
            sacc[0][jt] = MFMA(a0, bb, sacc[0][jt]);
            sacc[1][jt] = MFMA(a1, bb, sacc[1][jt]);
        }
    }

    #pragma unroll
    for (int jt = 0; jt < 5; jt++) {
        float bia = sBias[jq * 80 + jt * 16 + lr];
        #pragma unroll
        for (int mi = 0; mi < 2; mi++)
            #pragma unroll
            for (int r = 0; r < 4; r++)
                sacc[mi][jt][r] = sacc[mi][jt][r] * 0.0625f + bia;
    }
    // partial row max over this wave's j range
    #pragma unroll
    for (int mi = 0; mi < 2; mi++)
        #pragma unroll
        for (int r = 0; r < 4; r++) {
            float mx = -1e30f;
            #pragma unroll
            for (int jt = 0; jt < 5; jt++) mx = fmaxf(mx, sacc[mi][jt][r]);
            mx = fmaxf(mx, __shfl_xor(mx, 1));
            mx = fmaxf(mx, __shfl_xor(mx, 2));
            mx = fmaxf(mx, __shfl_xor(mx, 4));
            mx = fmaxf(mx, __shfl_xor(mx, 8));
            if (lr == 0) sPm[jq][mi * 16 + q * 4 + r] = mx;
        }
    __syncthreads();
    #pragma unroll
    for (int mi = 0; mi < 2; mi++)
        #pragma unroll
        for (int r = 0; r < 4; r++) {
            int row = mi * 16 + q * 4 + r;
            float rm = fmaxf(fmaxf(sPm[0][row], sPm[1][row]), fmaxf(sPm[2][row], sPm[3][row]));
            float ss = 0.0f;
            #pragma unroll
            for (int jt = 0; jt < 5; jt++) {
                float e = __expf(sacc[mi][jt][r] - rm);
                sacc[mi][jt][r] = e;
                ss += e;
            }
            ss += __shfl_xor(ss, 1);
            ss += __shfl_xor(ss, 2);
            ss += __shfl_xor(ss, 4);
            ss += __shfl_xor(ss, 8);
            if (lr == 0) sPs[jq][row] = ss;
        }
    __syncthreads();
    #pragma unroll
    for (int mi = 0; mi < 2; mi++)
        #pragma unroll
        for (int r = 0; r < 4; r++) {
            int row = mi * 16 + q * 4 + r;
            float inv = 1.0f / (sPs[0][row] + sPs[1][row] + sPs[2][row] + sPs[3][row]);
            #pragma unroll
            for (int jt = 0; jt < 5; jt++)
                sP[row][jq * 80 + jt * 16 + lr] = f2bf(sacc[mi][jt][r] * inv);
        }
    __syncthreads();

    // PV: all 32 rows x e in [jq*64, +64)
    const u16* vbase = vt + (size_t)b * EE * GP;
    f32x4 oacc[2][4];
    #pragma unroll
    for (int mi = 0; mi < 2; mi++)
        #pragma unroll
        for (int ni = 0; ni < 4; ni++) oacc[mi][ni] = {0.0f, 0.0f, 0.0f, 0.0f};

    #pragma unroll
    for (int ks = 0; ks < 10; ks++) {
        bf16x8 a0 = *(const bf16x8*)(&sP[lr][ks * 32 + lk]);
        bf16x8 a1 = *(const bf16x8*)(&sP[16 + lr][ks * 32 + lk]);
        #pragma unroll
        for (int ni = 0; ni < 4; ni++) {
            bf16x8 vv = *(const bf16x8*)(vbase + ((size_t)(jq * 64 + ni * 16 + lr)) * GP + ks * 32 + lk);
            oacc[0][ni] = MFMA(a0, vv, oacc[0][ni]);
            oacc[1][ni] = MFMA(a1, vv, oacc[1][ni]);
        }
    }
    #pragma unroll
    for (int mi = 0; mi < 2; mi++)
        #pragma unroll
        for (int ni = 0; ni < 4; ni++) {
            int col = jq * 64 + ni * 16 + lr;
            #pragma unroll
            for (int r = 0; r < 4; r++) {
                int row = mi * 16 + q * 4 + r;
                aob[((size_t)(b * GP + t0 + row)) * 256 + col] = f2bf(oacc[mi][ni][r]);
            }
        }
}

// ------------- head part 1: graph embed -> fixed context -> u[b] -------------
__global__ __launch_bounds__(256) void final1_kernel(
    const float* __restrict__ h, const float* __restrict__ obs,
    const float* __restrict__ w_fc, const float* __restrict__ w_pn,
    float* __restrict__ u)
{
    int b = blockIdx.x;
    int t = threadIdx.x;
    __shared__ float ges[EE];
    __shared__ float fcs[EE];

    float acc = 0.0f, vlen = 0.0f;
    for (int g = 0; g < GG; g++) {
        float m = obs[((size_t)b * GG + g) * 9 + 8];
        vlen += m;
        acc += h[((size_t)b * GP + g) * EE + t] * m;
    }
    ges[t] = acc / vlen;
    __syncthreads();

    float fc = 0.0f;
    for (int kk = 0; kk < EE; kk++) fc += ges[kk] * w_fc[kk * EE + t];
    fcs[t] = fc;
    __syncthreads();

    const float4* wp = reinterpret_cast<const float4*>(w_pn + (size_t)t * 3 * EE);
    float ua = 0.0f;
    for (int kk = 0; kk < EE / 4; kk++) {
        float4 w = wp[kk];
        ua += w.x * fcs[kk * 4] + w.y * fcs[kk * 4 + 1] +
              w.z * fcs[kk * 4 + 2] + w.w * fcs[kk * 4 + 3];
    }
    u[(size_t)b * EE + t] = ua;
}

// ------------- head part 2: compat -> tanh clip -> masked softmax -------------
__global__ __launch_bounds__(128) void final2_kernel(
    const float* __restrict__ h, const float* __restrict__ obs,
    const float* __restrict__ u, float* __restrict__ out)
{
    int b = blockIdx.x;
    int t = threadIdx.x;
    __shared__ float us[EE];
    __shared__ float red[8];
    us[t]       = u[(size_t)b * EE + t];
    us[t + 128] = u[(size_t)b * EE + t + 128];
    __syncthreads();

    float logit = -INFINITY;
    float m = 0.0f;
    if (t < LHN) {
        int g = IHN + t;
        m = obs[((size_t)b * GG + g) * 9 + 8];
        const float4* hr = reinterpret_cast<const float4*>(h + ((size_t)b * GP + g) * EE);
        float c = 0.0f;
        for (int kk = 0; kk < EE / 4; kk++) {
            float4 hv = hr[kk];
            c += hv.x * us[kk * 4] + hv.y * us[kk * 4 + 1] +
                 hv.z * us[kk * 4 + 2] + hv.w * us[kk * 4 + 3];
        }
        c *= m;
        c *= 0.0625f;
        logit = tanhf(c) * 10.0f;
    }
    float bm = blockReduceMax(logit, red);
    float e  = (t < LHN) ? __expf(logit - bm) : 0.0f;
    float bs = blockReduceSum(e, red);
    float p  = e / bs;
    float masked = (t < LHN) ? (p * m + 1e-20f) : 0.0f;
    float bs2 = blockReduceSum(masked, red);
    if (t < LHN) out[(size_t)b * LHN + t] = masked / bs2;
}

extern "C" void kernel_launch(void* const* d_in, const int* in_sizes, int n_in,
                              void* d_out, int out_size, void* d_ws, size_t ws_size,
                              hipStream_t stream) {
    const float* obs   = (const float*)d_in[0];
    const float* wi1   = (const float*)d_in[1];
    const float* bi1   = (const float*)d_in[2];
    const float* wi2   = (const float*)d_in[3];
    const float* bi2   = (const float*)d_in[4];
    const float* wl1   = (const float*)d_in[5];
    const float* bl1   = (const float*)d_in[6];
    const float* wl2   = (const float*)d_in[7];
    const float* bl2   = (const float*)d_in[8];
    const float* wn1   = (const float*)d_in[9];
    const float* bn1   = (const float*)d_in[10];
    const float* wn2   = (const float*)d_in[11];
    const float* bn2   = (const float*)d_in[12];
    const float* e_wq  = (const float*)d_in[13];
    const float* e_wk  = (const float*)d_in[14];
    const float* e_wv  = (const float*)d_in[15];
    const float* e_wo  = (const float*)d_in[16];
    const float* e_wf1 = (const float*)d_in[17];
    const float* e_bf1 = (const float*)d_in[18];
    const float* e_wf2 = (const float*)d_in[19];
    const float* e_bf2 = (const float*)d_in[20];
    const float* w_pn  = (const float*)d_in[21];
    const float* w_fc  = (const float*)d_in[22];
    float* outp = (float*)d_out;

    // ---- compact workspace layout: 254,017,536 B total ----
    char* wsc = (char*)d_ws;
    float* h    = (float*)wsc;
    u16*   hb   = (u16*)(wsc + 83886080);
    u16*   qaob = (u16*)(wsc + 125829120);   // qb, later aob
    u16*   kb   = (u16*)(wsc + 167772160);
    u16*   vt   = (u16*)(wsc + 209715200);
    u16*   wT   = (u16*)(wsc + 251658240);
    float* ubuf = (float*)(wsc + 253755392);
    u16*   hidb = kb;  // overlays kb+vt (disjoint lifetime)

    prep_kernel<<<dim3(512, 12), 256, 0, stream>>>(e_wq, e_wk, e_wv, e_wo, e_wf1, e_wf2, wT);
    pad_kernel<<<BB, 256, 0, stream>>>(h, hb);
    embed_seg<ILN, IHN, 0><<<IHN * BB / 32, 256, 0, stream>>>(obs, wi1, bi1, wi2, bi2, h, hb);
    embed_seg<8, LHN, IHN><<<LHN * BB / 32, 256, 0, stream>>>(obs, wl1, bl1, wl2, bl2, h, hb);
    embed_seg<6, 1, IHN + LHN><<<BB / 32, 256, 0, stream>>>(obs, wn1, bn1, wn2, bn2, h, hb);

    const size_t WL = 524288;
    for (int l = 0; l < NL; l++) {
        u16* wqkvT = wT + l * WL;
        u16* woT   = wqkvT + 196608;
        u16* w1T   = wqkvT + 262144;
        u16* w2T   = wqkvT + 393216;
        const float* bf1 = e_bf1 + (size_t)l * FFH;
        const float* bf2 = e_bf2 + (size_t)l * EE;

        qkv_gemm<<<dim3(MT / 128, 6), 256, 0, stream>>>(hb, wqkvT, qaob, kb, vt);
        attn_core<<<2560, 256, 0, stream>>>(qaob, kb, vt, obs, qaob);
        gemmln_kernel<4, 256, 256, false><<<MT / 128, 512, 0, stream>>>(qaob, woT, nullptr, h, hb);
        ff1_gemm<<<dim3(MT / 128, 4), 256, 0, stream>>>(hb, w1T, bf1, hidb);
        gemmln_kernel<8, 512, 512, true><<<MT / 128, 512, 0, stream>>>(hidb, w2T, bf2, h, hb);
    }
    final1_kernel<<<BB, 256, 0, stream>>>(h, obs, w_fc, w_pn, ubuf);
    final2_kernel<<<BB, 128, 0, stream>>>(h, obs, ubuf, outp);
}

// Round 9
// 769.455 us; speedup vs baseline: 1.3293x; 1.1728x over previous
//
#include <hip/hip_runtime.h>
#include <math.h>

static constexpr int BB   = 256;   // batch
static constexpr int IHN  = 200;   // internal tokens
static constexpr int ILN  = 6;     // internal feature dim
static constexpr int LHN  = 100;   // leaf tokens
static constexpr int EE   = 256;   // embed dim
static constexpr int FFH  = 512;   // ff hidden
static constexpr int NL   = 2;     // layers
static constexpr int GG   = 301;   // real tokens
static constexpr int GP   = 320;   // padded tokens (10 x 32)
static constexpr int MT   = BB * GP;  // 81920 total token rows

typedef unsigned short u16;
typedef short bf16x8 __attribute__((ext_vector_type(8)));
typedef float f32x4 __attribute__((ext_vector_type(4)));

#define MFMA(a, b, c) __builtin_amdgcn_mfma_f32_16x16x32_bf16((a), (b), (c), 0, 0, 0)

__device__ __forceinline__ u16 f2bf(float f) {
    union { float f; unsigned u; } v; v.f = f;
    unsigned r = v.u + 0x7FFFu + ((v.u >> 16) & 1u);
    return (u16)(r >> 16);
}

// ---------------- wave/block reduction helpers (wave = 64) ----------------
__device__ __forceinline__ float waveReduceSum(float v) {
    for (int o = 32; o > 0; o >>= 1) v += __shfl_down(v, o, 64);
    return v;
}
__device__ __forceinline__ float waveReduceMax(float v) {
    for (int o = 32; o > 0; o >>= 1) v = fmaxf(v, __shfl_down(v, o, 64));
    return v;
}
__device__ __forceinline__ float blockReduceSum(float v, float* red) {
    int lane = threadIdx.x & 63;
    int w    = threadIdx.x >> 6;
    int nw   = (blockDim.x + 63) >> 6;
    v = waveReduceSum(v);
    if (lane == 0) red[w] = v;
    __syncthreads();
    if (threadIdx.x < 64) {
        float x = (lane < nw) ? red[lane] : 0.0f;
        x = waveReduceSum(x);
        if (lane == 0) red[0] = x;
    }
    __syncthreads();
    float r = red[0];
    __syncthreads();
    return r;
}
__device__ __forceinline__ float blockReduceMax(float v, float* red) {
    int lane = threadIdx.x & 63;
    int w    = threadIdx.x >> 6;
    int nw   = (blockDim.x + 63) >> 6;
    v = waveReduceMax(v);
    if (lane == 0) red[w] = v;
    __syncthreads();
    if (threadIdx.x < 64) {
        float x = (lane < nw) ? red[lane] : -INFINITY;
        x = waveReduceMax(x);
        if (lane == 0) red[0] = x;
    }
    __syncthreads();
    float r = red[0];
    __syncthreads();
    return r;
}

// --------- staging: global -> LDS tile [rows][64] bf16, XOR-swizzled ---------
__device__ __forceinline__ void stage_swz(const u16* src, int strideShorts, int k0,
                                          u16* ldsTile, int nChunks, int wave,
                                          int nWaves, int lane)
{
    for (int c = wave; c < nChunks; c += nWaves) {
        int o = c * 1024 + lane * 16;
        int row = o >> 7;
        int cb = (o & 127) ^ ((row & 7) << 4);
        const u16* g = src + (size_t)row * strideShorts + k0 + (cb >> 1);
        __builtin_amdgcn_global_load_lds(
            (const __attribute__((address_space(1))) unsigned int*)g,
            (__attribute__((address_space(3))) unsigned int*)((char*)ldsTile + c * 1024),
            16, 0, 0);
    }
}

__device__ __forceinline__ bf16x8 lds_frag(const u16* tile, int row, int kk, int q)
{
    int cb = (kk * 64 + q * 16) ^ ((row & 7) << 4);
    return *(const bf16x8*)((const char*)tile + row * 128 + cb);
}

// ------------- prep: transpose encoder weights to bf16 [N][K] -------------
__global__ __launch_bounds__(256) void prep_kernel(
    const float* __restrict__ wq, const float* __restrict__ wk,
    const float* __restrict__ wv, const float* __restrict__ wo,
    const float* __restrict__ wf1, const float* __restrict__ wf2,
    u16* __restrict__ wT)
{
    int l = blockIdx.y / 6, m = blockIdx.y % 6;
    int idx = blockIdx.x * 256 + threadIdx.x;
    u16* dst = wT + (size_t)l * 524288;
    if (m < 4) {
        if (idx >= EE * EE) return;
        const float* src = (m == 0 ? wq : m == 1 ? wk : m == 2 ? wv : wo) + (size_t)l * EE * EE;
        int r = idx >> 8, c = idx & 255;
        dst[m * 65536 + idx] = f2bf(src[(size_t)c * EE + r]);
    } else if (m == 4) {
        if (idx >= FFH * EE) return;
        const float* src = wf1 + (size_t)l * EE * FFH;
        int r = idx >> 8, c = idx & 255;
        dst[262144 + idx] = f2bf(src[(size_t)c * FFH + r]);
    } else {
        if (idx >= EE * FFH) return;
        const float* src = wf2 + (size_t)l * FFH * EE;
        int r = idx >> 9, c = idx & 511;
        dst[393216 + idx] = f2bf(src[(size_t)c * EE + r]);
    }
}

// ---------- embed (segment version): 32 tokens/block, w2 col in regs ----------
template<int IND, int SEG, int G0>
__global__ __launch_bounds__(256) void embed_seg(
    const float* __restrict__ obs,
    const float* __restrict__ w1, const float* __restrict__ b1,
    const float* __restrict__ w2, const float* __restrict__ b2,
    float* __restrict__ h, u16* __restrict__ hb)
{
    __shared__ float xs[32][9];
    __shared__ float hid[32][33];
    int t = threadIdx.x;
    int fi0 = blockIdx.x * 32;

    for (int p = t; p < 32 * 9; p += 256) {
        int tok = p / 9, f = p % 9;
        int fi = fi0 + tok;
        int b = fi / SEG, g = G0 + fi % SEG;
        xs[tok][f] = obs[((size_t)b * GG + g) * 9 + f];
    }
    __syncthreads();

    #pragma unroll
    for (int p = 0; p < 4; p++) {
        int idx = p * 256 + t;
        int tok = idx >> 5, hcol = idx & 31;
        float a = b1[hcol];
        #pragma unroll
        for (int i = 0; i < IND; i++) a += xs[tok][i] * w1[i * 32 + hcol];
        hid[tok][hcol] = (a > 0.0f) ? a : 0.01f * a;
    }
    __syncthreads();

    float w2c[32];
    #pragma unroll
    for (int j = 0; j < 32; j++) w2c[j] = w2[j * EE + t];
    float bb = b2[t];
    for (int tok = 0; tok < 32; tok++) {
        int fi = fi0 + tok;
        int b = fi / SEG, g = G0 + fi % SEG;
        float a = bb;
        #pragma unroll
        for (int j = 0; j < 32; j++) a += hid[tok][j] * w2c[j];
        size_t o = ((size_t)b * GP + g) * EE + t;
        h[o] = a; hb[o] = f2bf(a);
    }
}

// zero the pad rows g in [GG, GP)
__global__ __launch_bounds__(256) void pad_kernel(float* __restrict__ h, u16* __restrict__ hb)
{
    int b = blockIdx.x, t = threadIdx.x;
    for (int g = GG; g < GP; g++) {
        size_t o = ((size_t)b * GP + g) * EE + t;
        h[o] = 0.0f; hb[o] = 0;
    }
}

// --------- QKV GEMM: 128x128 tile, epilogue scatters Q/K rows + V^T ---------
__global__ __launch_bounds__(256) void qkv_gemm(
    const u16* __restrict__ hb, const u16* __restrict__ wqkvT,
    u16* __restrict__ qb, u16* __restrict__ kb, u16* __restrict__ vt)
{
    __shared__ __align__(16) u16 sA[128 * 64];
    __shared__ __align__(16) u16 sB[128 * 64];
    int tid = threadIdx.x, lane = tid & 63, w = tid >> 6;
    int wm = w >> 1, wn = w & 1;
    int lr = lane & 15, q = lane >> 4;
    int brow = blockIdx.x * 128;
    int bcol = blockIdx.y * 128;

    f32x4 acc[4][4];
    #pragma unroll
    for (int i = 0; i < 4; i++)
        #pragma unroll
        for (int j = 0; j < 4; j++) acc[i][j] = {0.0f, 0.0f, 0.0f, 0.0f};

    for (int ks = 0; ks < 4; ks++) {
        __syncthreads();
        stage_swz(hb + (size_t)brow * 256, 256, ks * 64, sA, 16, w, 4, lane);
        stage_swz(wqkvT + (size_t)bcol * 256, 256, ks * 64, sB, 16, w, 4, lane);
        __syncthreads();
        #pragma unroll
        for (int kk = 0; kk < 2; kk++) {
            bf16x8 a[4], b[4];
            #pragma unroll
            for (int i = 0; i < 4; i++) {
                a[i] = lds_frag(sA, wm * 64 + i * 16 + lr, kk, q);
                b[i] = lds_frag(sB, wn * 64 + i * 16 + lr, kk, q);
            }
            #pragma unroll
            for (int mi = 0; mi < 4; mi++)
                #pragma unroll
                for (int ni = 0; ni < 4; ni++)
                    acc[mi][ni] = MFMA(a[mi], b[ni], acc[mi][ni]);
        }
    }

    if (bcol < 512) {
        u16* dst = (bcol < 256) ? qb : kb;
        int cOff = bcol & 255;
        #pragma unroll
        for (int mi = 0; mi < 4; mi++)
            #pragma unroll
            for (int ni = 0; ni < 4; ni++) {
                int col = cOff + wn * 64 + ni * 16 + lr;
                #pragma unroll
                for (int j = 0; j < 4; j++) {
                    int rowG = brow + wm * 64 + mi * 16 + q * 4 + j;
                    dst[(size_t)rowG * 256 + col] = f2bf(acc[mi][ni][j]);
                }
            }
    } else {
        #pragma unroll
        for (int mi = 0; mi < 4; mi++) {
            int rowG0 = brow + wm * 64 + mi * 16 + q * 4;
            int b0 = rowG0 / GP;
            int g0 = rowG0 - b0 * GP;
            #pragma unroll
            for (int ni = 0; ni < 4; ni++) {
                int e = (bcol - 512) + wn * 64 + ni * 16 + lr;
                ushort4 u4;
                u4.x = f2bf(acc[mi][ni][0]);
                u4.y = f2bf(acc[mi][ni][1]);
                u4.z = f2bf(acc[mi][ni][2]);
                u4.w = f2bf(acc[mi][ni][3]);
                *(ushort4*)(vt + ((size_t)(b0 * EE + e)) * GP + g0) = u4;
            }
        }
    }
}

// --------- FF1 GEMM: 128x128 tile, epilogue bias+relu -> hidb bf16 ---------
__global__ __launch_bounds__(256) void ff1_gemm(
    const u16* __restrict__ hb, const u16* __restrict__ w1T,
    const float* __restrict__ bf1, u16* __restrict__ hidb)
{
    __shared__ __align__(16) u16 sA[128 * 64];
    __shared__ __align__(16) u16 sB[128 * 64];
    int tid = threadIdx.x, lane = tid & 63, w = tid >> 6;
    int wm = w >> 1, wn = w & 1;
    int lr = lane & 15, q = lane >> 4;
    int brow = blockIdx.x * 128;
    int bcol = blockIdx.y * 128;

    f32x4 acc[4][4];
    #pragma unroll
    for (int i = 0; i < 4; i++)
        #pragma unroll
        for (int j = 0; j < 4; j++) acc[i][j] = {0.0f, 0.0f, 0.0f, 0.0f};

    for (int ks = 0; ks < 4; ks++) {
        __syncthreads();
        stage_swz(hb + (size_t)brow * 256, 256, ks * 64, sA, 16, w, 4, lane);
        stage_swz(w1T + (size_t)bcol * 256, 256, ks * 64, sB, 16, w, 4, lane);
        __syncthreads();
        #pragma unroll
        for (int kk = 0; kk < 2; kk++) {
            bf16x8 a[4], b[4];
            #pragma unroll
            for (int i = 0; i < 4; i++) {
                a[i] = lds_frag(sA, wm * 64 + i * 16 + lr, kk, q);
                b[i] = lds_frag(sB, wn * 64 + i * 16 + lr, kk, q);
            }
            #pragma unroll
            for (int mi = 0; mi < 4; mi++)
                #pragma unroll
                for (int ni = 0; ni < 4; ni++)
                    acc[mi][ni] = MFMA(a[mi], b[ni], acc[mi][ni]);
        }
    }

    #pragma unroll
    for (int ni = 0; ni < 4; ni++) {
        int col = bcol + wn * 64 + ni * 16 + lr;
        float bias = bf1[col];
        #pragma unroll
        for (int mi = 0; mi < 4; mi++)
            #pragma unroll
            for (int j = 0; j < 4; j++) {
                int rowG = brow + wm * 64 + mi * 16 + q * 4 + j;
                float v = acc[mi][ni][j] + bias;
                hidb[(size_t)rowG * 512 + col] = f2bf(fmaxf(v, 0.0f));
            }
    }
}

// ---- GEMM + residual + LayerNorm: BM=128, BN=256(full row), 8 waves ----
template<int KSTEPS, int ASTR, int BSTR, bool HASB>
__global__ __launch_bounds__(512) void gemmln_kernel(
    const u16* __restrict__ A, const u16* __restrict__ Bw,
    const float* __restrict__ bias, float* __restrict__ h, u16* __restrict__ hb)
{
    __shared__ __align__(16) u16 sA[128 * 64];   // 16 KB
    __shared__ __align__(16) u16 sB[256 * 64];   // 32 KB
    int tid = threadIdx.x, lane = tid & 63, w = tid >> 6;
    int wm = w >> 2, wn = w & 3;
    int lr = lane & 15, q = lane >> 4;
    int brow = blockIdx.x * 128;

    f32x4 acc[4][4];
    #pragma unroll
    for (int i = 0; i < 4; i++)
        #pragma unroll
        for (int j = 0; j < 4; j++) acc[i][j] = {0.0f, 0.0f, 0.0f, 0.0f};

    for (int ks = 0; ks < KSTEPS; ks++) {
        __syncthreads();
        stage_swz(A + (size_t)brow * ASTR, ASTR, ks * 64, sA, 16, w, 8, lane);
        stage_swz(Bw, BSTR, ks * 64, sB, 32, w, 8, lane);
        __syncthreads();
        #pragma unroll
        for (int kk = 0; kk < 2; kk++) {
            bf16x8 a[4], b[4];
            #pragma unroll
            for (int i = 0; i < 4; i++) {
                a[i] = lds_frag(sA, wm * 64 + i * 16 + lr, kk, q);
                b[i] = lds_frag(sB, wn * 64 + i * 16 + lr, kk, q);
            }
            #pragma unroll
            for (int mi = 0; mi < 4; mi++)
                #pragma unroll
                for (int ni = 0; ni < 4; ni++)
                    acc[mi][ni] = MFMA(a[mi], b[ni], acc[mi][ni]);
        }
    }

    __syncthreads();
    float* sPart = (float*)sA;           // [4 wn][128 row][2]

    #pragma unroll
    for (int ni = 0; ni < 4; ni++) {
        int col = wn * 64 + ni * 16 + lr;
        float bv = HASB ? bias[col] : 0.0f;
        #pragma unroll
        for (int mi = 0; mi < 4; mi++)
            #pragma unroll
            for (int j = 0; j < 4; j++) {
                int rowG = brow + wm * 64 + mi * 16 + q * 4 + j;
                acc[mi][ni][j] += bv + h[(size_t)rowG * 256 + col];
            }
    }
    #pragma unroll
    for (int mi = 0; mi < 4; mi++)
        #pragma unroll
        for (int j = 0; j < 4; j++) {
            float s1 = 0.0f, s2 = 0.0f;
            #pragma unroll
            for (int ni = 0; ni < 4; ni++) {
                float v = acc[mi][ni][j];
                s1 += v; s2 += v * v;
            }
            s1 += __shfl_xor(s1, 1); s2 += __shfl_xor(s2, 1);
            s1 += __shfl_xor(s1, 2); s2 += __shfl_xor(s2, 2);
            s1 += __shfl_xor(s1, 4); s2 += __shfl_xor(s2, 4);
            s1 += __shfl_xor(s1, 8); s2 += __shfl_xor(s2, 8);
            if (lr == 0) {
                int lrow = wm * 64 + mi * 16 + q * 4 + j;
                sPart[(wn * 128 + lrow) * 2 + 0] = s1;
                sPart[(wn * 128 + lrow) * 2 + 1] = s2;
            }
        }
    __syncthreads();

    #pragma unroll
    for (int mi = 0; mi < 4; mi++)
        #pragma unroll
        for (int j = 0; j < 4; j++) {
            int lrow = wm * 64 + mi * 16 + q * 4 + j;
            float s1 = sPart[lrow * 2] + sPart[(128 + lrow) * 2] +
                       sPart[(256 + lrow) * 2] + sPart[(384 + lrow) * 2];
            float s2 = sPart[lrow * 2 + 1] + sPart[(128 + lrow) * 2 + 1] +
                       sPart[(256 + lrow) * 2 + 1] + sPart[(384 + lrow) * 2 + 1];
            float mean = s1 * (1.0f / 256.0f);
            float var  = s2 * (1.0f / 256.0f) - mean * mean;
            float rstd = rsqrtf(var + 1e-5f);
            int rowG = brow + lrow;
            #pragma unroll
            for (int ni = 0; ni < 4; ni++) {
                int col = wn * 64 + ni * 16 + lr;
                float v = (acc[mi][ni][j] - mean) * rstd;
                size_t o = (size_t)rowG * 256 + col;
                h[o] = v; hb[o] = f2bf(v);
            }
        }
}

// ------- attention core (flash-LDS): K/V staged via global_load_lds with
// counted-vmcnt prefetch; two-pass softmax; P in LDS (stride 344, ~2-way).
// 64 q-rows/block, 512 thr (8 waves: wm row-quarter, wn j/e-half).
// XCD-bijective swizzle keeps a batch's K/V on one XCD's L2.
// aob may alias qb: Q read into regs at block start, aob written at end,
// both only this block's own 64 rows.
__global__ __launch_bounds__(512) void attn_core(
    const u16* __restrict__ qb, const u16* __restrict__ kb,
    const u16* __restrict__ vt, const float* __restrict__ obs,
    u16* __restrict__ aob)
{
    __shared__ __align__(16) u16 sKV[2][16384];   // 64 KB: K tiles, then V tiles
    __shared__ __align__(16) u16 sP[64 * 344];    // 43 KB, stride 344 (2-way banks)
    __shared__ float sBias[320];
    __shared__ float sPm[2][64], sPs[2][64];

    int id = blockIdx.x;                 // 1280 blocks
    int xcd = id & 7, jj = id >> 3;      // jj in [0,160)
    int tile = jj % 5, bgrp = jj / 5;    // bgrp in [0,32)
    int b = xcd + 8 * bgrp;              // bijective batch
    int t0 = tile * 64;

    int tid = threadIdx.x, w = tid >> 6, lane = tid & 63;
    int wm = w >> 1, wn = w & 1;         // row-quarter (16 rows), j/e-half
    int lr = lane & 15, q = lane >> 4, lk = q * 8;

    if (tid < 320) {
        float msk = (tid < GG) ? obs[((size_t)b * GG + tid) * 9 + 8] : 0.0f;
        sBias[tid] = (1.0f - msk) * -1e9f;
    }

    // Q fragments for this wave's 16 rows: 8 x bf16x8 (all 256 k)
    const u16* qbase = qb + ((size_t)(b * GP + t0 + wm * 16 + lr)) * 256;
    bf16x8 af[8];
    #pragma unroll
    for (int k8 = 0; k8 < 8; k8++) af[k8] = *(const bf16x8*)(qbase + k8 * 32 + lk);

    const u16* kbase = kb + ((size_t)(b * GP + t0 * 0)) * 256;  // keys start at 0
    const u16* vbase = vt + (size_t)b * EE * GP;

    // ---- scores: 5 K-tiles of 64 keys, double-buffered, counted vmcnt ----
    // stage K0 (4 loads/thread)
    #pragma unroll
    for (int r = 0; r < 4; r++)
        stage_swz(kb + ((size_t)b * GP) * 256, 256, r * 64, sKV[0] + r * 4096, 8, w, 8, lane);

    f32x4 sacc[10];
    #pragma unroll
    for (int s = 0; s < 10; s++) sacc[s] = {0.0f, 0.0f, 0.0f, 0.0f};

    for (int t = 0; t < 5; t++) {
        if (t < 4) {
            #pragma unroll
            for (int r = 0; r < 4; r++)
                stage_swz(kb + ((size_t)(b * GP + (t + 1) * 64)) * 256, 256, r * 64,
                          sKV[(t + 1) & 1] + r * 4096, 8, w, 8, lane);
            asm volatile("s_waitcnt vmcnt(4)" ::: "memory");
        } else {
            asm volatile("s_waitcnt vmcnt(0)" ::: "memory");
        }
        __builtin_amdgcn_s_barrier();
        const u16* kbuf = sKV[t & 1];
        #pragma unroll
        for (int ks = 0; ks < 4; ks++)
            #pragma unroll
            for (int kk = 0; kk < 2; kk++) {
                bf16x8 a = af[ks * 2 + kk];
                #pragma unroll
                for (int l = 0; l < 2; l++) {
                    int jl = (wn * 2 + l) * 16 + lr;
                    bf16x8 bb = lds_frag(kbuf + ks * 4096, jl, kk, q);
                    sacc[t * 2 + l] = MFMA(a, bb, sacc[t * 2 + l]);
                }
            }
        __builtin_amdgcn_s_barrier();
    }

    // ---- bias + softmax (two partials over wn) ----
    #pragma unroll
    for (int s = 0; s < 10; s++) {
        int j = (s >> 1) * 64 + (wn * 2 + (s & 1)) * 16 + lr;
        float bia = sBias[j];
        #pragma unroll
        for (int r = 0; r < 4; r++) sacc[s][r] = sacc[s][r] * 0.0625f + bia;
    }
    #pragma unroll
    for (int r = 0; r < 4; r++) {
        float mx = -1e30f;
        #pragma unroll
        for (int s = 0; s < 10; s++) mx = fmaxf(mx, sacc[s][r]);
        mx = fmaxf(mx, __shfl_xor(mx, 1));
        mx = fmaxf(mx, __shfl_xor(mx, 2));
        mx = fmaxf(mx, __shfl_xor(mx, 4));
        mx = fmaxf(mx, __shfl_xor(mx, 8));
        if (lr == 0) sPm[wn][wm * 16 + q * 4 + r] = mx;
    }
    __syncthreads();

    // prefetch V0 into buf0 (K compute fully done); softmax hides its latency
    stage_swz(vbase, GP, 0 * 64, sKV[0], 32, w, 8, lane);

    #pragma unroll
    for (int r = 0; r < 4; r++) {
        int row = wm * 16 + q * 4 + r;
        float rm = fmaxf(sPm[0][row], sPm[1][row]);
        float ss = 0.0f;
        #pragma unroll
        for (int s = 0; s < 10; s++) {
            float e = __expf(sacc[s][r] - rm);
            sacc[s][r] = e;
            ss += e;
        }
        ss += __shfl_xor(ss, 1);
        ss += __shfl_xor(ss, 2);
        ss += __shfl_xor(ss, 4);
        ss += __shfl_xor(ss, 8);
        if (lr == 0) sPs[wn][row] = ss;
    }
    __syncthreads();
    #pragma unroll
    for (int r = 0; r < 4; r++) {
        int row = wm * 16 + q * 4 + r;
        float inv = 1.0f / (sPs[0][row] + sPs[1][row]);
        #pragma unroll
        for (int s = 0; s < 10; s++) {
            int j = (s >> 1) * 64 + (wn * 2 + (s & 1)) * 16 + lr;
            sP[row * 344 + j] = f2bf(sacc[s][r] * inv);
        }
    }
    __syncthreads();

    // ---- PV: 5 V-tiles of 64 keys (V^T [256 e][64 g]), double-buffered ----
    f32x4 oacc[8];
    #pragma unroll
    for (int n = 0; n < 8; n++) oacc[n] = {0.0f, 0.0f, 0.0f, 0.0f};

    for (int c = 0; c < 5; c++) {
        if (c < 4) {
            stage_swz(vbase, GP, (c + 1) * 64, sKV[(c + 1) & 1], 32, w, 8, lane);
            asm volatile("s_waitcnt vmcnt(4)" ::: "memory");
        } else {
            asm volatile("s_waitcnt vmcnt(0)" ::: "memory");
        }
        __builtin_amdgcn_s_barrier();
        const u16* vbuf = sKV[c & 1];
        #pragma unroll
        for (int kk = 0; kk < 2; kk++) {
            bf16x8 a = *(const bf16x8*)(sP + (wm * 16 + lr) * 344 + c * 64 + kk * 32 + lk);
            #pragma unroll
            for (int n = 0; n < 8; n++) {
                bf16x8 vv = lds_frag(vbuf, wn * 128 + n * 16 + lr, kk, q);
                oacc[n] = MFMA(a, vv, oacc[n]);
            }
        }
        __builtin_amdgcn_s_barrier();
    }

    #pragma unroll
    for (int n = 0; n < 8; n++) {
        int col = wn * 128 + n * 16 + lr;
        #pragma unroll
        for (int r = 0; r < 4; r++) {
            int row = wm * 16 + q * 4 + r;
            aob[((size_t)(b * GP + t0 + row)) * 256 + col] = f2bf(oacc[n][r]);
        }
    }
}

// ------------- head part 1: graph embed -> fixed context -> u[b] -------------
__global__ __launch_bounds__(256) void final1_kernel(
    const float* __restrict__ h, const float* __restrict__ obs,
    const float* __restrict__ w_fc, const float* __restrict__ w_pn,
    float* __restrict__ u)
{
    int b = blockIdx.x;
    int t = threadIdx.x;
    __shared__ float ges[EE];
    __shared__ float fcs[EE];

    float acc = 0.0f, vlen = 0.0f;
    for (int g = 0; g < GG; g++) {
        float m = obs[((size_t)b * GG + g) * 9 + 8];
        vlen += m;
        acc += h[((size_t)b * GP + g) * EE + t] * m;
    }
    ges[t] = acc / vlen;
    __syncthreads();

    float fc = 0.0f;
    for (int kk = 0; kk < EE; kk++) fc += ges[kk] * w_fc[kk * EE + t];
    fcs[t] = fc;
    __syncthreads();

    const float4* wp = reinterpret_cast<const float4*>(w_pn + (size_t)t * 3 * EE);
    float ua = 0.0f;
    for (int kk = 0; kk < EE / 4; kk++) {
        float4 w = wp[kk];
        ua += w.x * fcs[kk * 4] + w.y * fcs[kk * 4 + 1] +
              w.z * fcs[kk * 4 + 2] + w.w * fcs[kk * 4 + 3];
    }
    u[(size_t)b * EE + t] = ua;
}

// ------------- head part 2: compat -> tanh clip -> masked softmax -------------
__global__ __launch_bounds__(128) void final2_kernel(
    const float* __restrict__ h, const float* __restrict__ obs,
    const float* __restrict__ u, float* __restrict__ out)
{
    int b = blockIdx.x;
    int t = threadIdx.x;
    __shared__ float us[EE];
    __shared__ float red[8];
    us[t]       = u[(size_t)b * EE + t];
    us[t + 128] = u[(size_t)b * EE + t + 128];
    __syncthreads();

    float logit = -INFINITY;
    float m = 0.0f;
    if (t < LHN) {
        int g = IHN + t;
        m = obs[((size_t)b * GG + g) * 9 + 8];
        const float4* hr = reinterpret_cast<const float4*>(h + ((size_t)b * GP + g) * EE);
        float c = 0.0f;
        for (int kk = 0; kk < EE / 4; kk++) {
            float4 hv = hr[kk];
            c += hv.x * us[kk * 4] + hv.y * us[kk * 4 + 1] +
                 hv.z * us[kk * 4 + 2] + hv.w * us[kk * 4 + 3];
        }
        c *= m;
        c *= 0.0625f;
        logit = tanhf(c) * 10.0f;
    }
    float bm = blockReduceMax(logit, red);
    float e  = (t < LHN) ? __expf(logit - bm) : 0.0f;
    float bs = blockReduceSum(e, red);
    float p  = e / bs;
    float masked = (t < LHN) ? (p * m + 1e-20f) : 0.0f;
    float bs2 = blockReduceSum(masked, red);
    if (t < LHN) out[(size_t)b * LHN + t] = masked / bs2;
}

extern "C" void kernel_launch(void* const* d_in, const int* in_sizes, int n_in,
                              void* d_out, int out_size, void* d_ws, size_t ws_size,
                              hipStream_t stream) {
    const float* obs   = (const float*)d_in[0];
    const float* wi1   = (const float*)d_in[1];
    const float* bi1   = (const float*)d_in[2];
    const float* wi2   = (const float*)d_in[3];
    const float* bi2   = (const float*)d_in[4];
    const float* wl1   = (const float*)d_in[5];
    const float* bl1   = (const float*)d_in[6];
    const float* wl2   = (const float*)d_in[7];
    const float* bl2   = (const float*)d_in[8];
    const float* wn1   = (const float*)d_in[9];
    const float* bn1   = (const float*)d_in[10];
    const float* wn2   = (const float*)d_in[11];
    const float* bn2   = (const float*)d_in[12];
    const float* e_wq  = (const float*)d_in[13];
    const float* e_wk  = (const float*)d_in[14];
    const float* e_wv  = (const float*)d_in[15];
    const float* e_wo  = (const float*)d_in[16];
    const float* e_wf1 = (const float*)d_in[17];
    const float* e_bf1 = (const float*)d_in[18];
    const float* e_wf2 = (const float*)d_in[19];
    const float* e_bf2 = (const float*)d_in[20];
    const float* w_pn  = (const float*)d_in[21];
    const float* w_fc  = (const float*)d_in[22];
    float* outp = (float*)d_out;

    // ---- compact workspace layout: 254,017,536 B total ----
    char* wsc = (char*)d_ws;
    float* h    = (float*)wsc;
    u16*   hb   = (u16*)(wsc + 83886080);
    u16*   qaob = (u16*)(wsc + 125829120);   // qb, later aob
    u16*   kb   = (u16*)(wsc + 167772160);
    u16*   vt   = (u16*)(wsc + 209715200);
    u16*   wT   = (u16*)(wsc + 251658240);
    float* ubuf = (float*)(wsc + 253755392);
    u16*   hidb = kb;  // overlays kb+vt (disjoint lifetime)

    prep_kernel<<<dim3(512, 12), 256, 0, stream>>>(e_wq, e_wk, e_wv, e_wo, e_wf1, e_wf2, wT);
    pad_kernel<<<BB, 256, 0, stream>>>(h, hb);
    embed_seg<ILN, IHN, 0><<<IHN * BB / 32, 256, 0, stream>>>(obs, wi1, bi1, wi2, bi2, h, hb);
    embed_seg<8, LHN, IHN><<<LHN * BB / 32, 256, 0, stream>>>(obs, wl1, bl1, wl2, bl2, h, hb);
    embed_seg<6, 1, IHN + LHN><<<BB / 32, 256, 0, stream>>>(obs, wn1, bn1, wn2, bn2, h, hb);

    const size_t WL = 524288;
    for (int l = 0; l < NL; l++) {
        u16* wqkvT = wT + l * WL;
        u16* woT   = wqkvT + 196608;
        u16* w1T   = wqkvT + 262144;
        u16* w2T   = wqkvT + 393216;
        const float* bf1 = e_bf1 + (size_t)l * FFH;
        const float* bf2 = e_bf2 + (size_t)l * EE;

        qkv_gemm<<<dim3(MT / 128, 6), 256, 0, stream>>>(hb, wqkvT, qaob, kb, vt);
        attn_core<<<1280, 512, 0, stream>>>(qaob, kb, vt, obs, qaob);
        gemmln_kernel<4, 256, 256, false><<<MT / 128, 512, 0, stream>>>(qaob, woT, nullptr, h, hb);
        ff1_gemm<<<dim3(MT / 128, 4), 256, 0, stream>>>(hb, w1T, bf1, hidb);
        gemmln_kernel<8, 512, 512, true><<<MT / 128, 512, 0, stream>>>(hidb, w2T, bf2, h, hb);
    }
    final1_kernel<<<BB, 256, 0, stream>>>(h, obs, w_fc, w_pn, ubuf);
    final2_kernel<<<BB, 128, 0, stream>>>(h, obs, ubuf, outp);
}

// Round 10
// 710.906 us; speedup vs baseline: 1.4387x; 1.0824x over previous
//
#include <hip/hip_runtime.h>
#include <math.h>

static constexpr int BB   = 256;   // batch
static constexpr int IHN  = 200;   // internal tokens
static constexpr int ILN  = 6;     // internal feature dim
static constexpr int LHN  = 100;   // leaf tokens
static constexpr int EE   = 256;   // embed dim
static constexpr int FFH  = 512;   // ff hidden
static constexpr int NL   = 2;     // layers
static constexpr int GG   = 301;   // real tokens
static constexpr int GP   = 320;   // padded tokens (10 x 32)
static constexpr int MT   = BB * GP;  // 81920 total token rows

typedef unsigned short u16;
typedef short bf16x8 __attribute__((ext_vector_type(8)));
typedef float f32x4 __attribute__((ext_vector_type(4)));

#define MFMA(a, b, c) __builtin_amdgcn_mfma_f32_16x16x32_bf16((a), (b), (c), 0, 0, 0)

__device__ __forceinline__ u16 f2bf(float f) {
    union { float f; unsigned u; } v; v.f = f;
    unsigned r = v.u + 0x7FFFu + ((v.u >> 16) & 1u);
    return (u16)(r >> 16);
}

// ---------------- wave/block reduction helpers (wave = 64) ----------------
__device__ __forceinline__ float waveReduceSum(float v) {
    for (int o = 32; o > 0; o >>= 1) v += __shfl_down(v, o, 64);
    return v;
}
__device__ __forceinline__ float waveReduceMax(float v) {
    for (int o = 32; o > 0; o >>= 1) v = fmaxf(v, __shfl_down(v, o, 64));
    return v;
}
__device__ __forceinline__ float blockReduceSum(float v, float* red) {
    int lane = threadIdx.x & 63;
    int w    = threadIdx.x >> 6;
    int nw   = (blockDim.x + 63) >> 6;
    v = waveReduceSum(v);
    if (lane == 0) red[w] = v;
    __syncthreads();
    if (threadIdx.x < 64) {
        float x = (lane < nw) ? red[lane] : 0.0f;
        x = waveReduceSum(x);
        if (lane == 0) red[0] = x;
    }
    __syncthreads();
    float r = red[0];
    __syncthreads();
    return r;
}
__device__ __forceinline__ float blockReduceMax(float v, float* red) {
    int lane = threadIdx.x & 63;
    int w    = threadIdx.x >> 6;
    int nw   = (blockDim.x + 63) >> 6;
    v = waveReduceMax(v);
    if (lane == 0) red[w] = v;
    __syncthreads();
    if (threadIdx.x < 64) {
        float x = (lane < nw) ? red[lane] : -INFINITY;
        x = waveReduceMax(x);
        if (lane == 0) red[0] = x;
    }
    __syncthreads();
    float r = red[0];
    __syncthreads();
    return r;
}

// --------- staging: global -> LDS tile [rows][64] bf16, XOR-swizzled ---------
__device__ __forceinline__ void stage_swz(const u16* src, int strideShorts, int k0,
                                          u16* ldsTile, int nChunks, int wave,
                                          int nWaves, int lane)
{
    for (int c = wave; c < nChunks; c += nWaves) {
        int o = c * 1024 + lane * 16;
        int row = o >> 7;
        int cb = (o & 127) ^ ((row & 7) << 4);
        const u16* g = src + (size_t)row * strideShorts + k0 + (cb >> 1);
        __builtin_amdgcn_global_load_lds(
            (const __attribute__((address_space(1))) unsigned int*)g,
            (__attribute__((address_space(3))) unsigned int*)((char*)ldsTile + c * 1024),
            16, 0, 0);
    }
}

__device__ __forceinline__ bf16x8 lds_frag(const u16* tile, int row, int kk, int q)
{
    int cb = (kk * 64 + q * 16) ^ ((row & 7) << 4);
    return *(const bf16x8*)((const char*)tile + row * 128 + cb);
}

// ------------- prep: transpose encoder weights to bf16 [N][K] -------------
__global__ __launch_bounds__(256) void prep_kernel(
    const float* __restrict__ wq, const float* __restrict__ wk,
    const float* __restrict__ wv, const float* __restrict__ wo,
    const float* __restrict__ wf1, const float* __restrict__ wf2,
    u16* __restrict__ wT)
{
    int l = blockIdx.y / 6, m = blockIdx.y % 6;
    int idx = blockIdx.x * 256 + threadIdx.x;
    u16* dst = wT + (size_t)l * 524288;
    if (m < 4) {
        if (idx >= EE * EE) return;
        const float* src = (m == 0 ? wq : m == 1 ? wk : m == 2 ? wv : wo) + (size_t)l * EE * EE;
        int r = idx >> 8, c = idx & 255;
        dst[m * 65536 + idx] = f2bf(src[(size_t)c * EE + r]);
    } else if (m == 4) {
        if (idx >= FFH * EE) return;
        const float* src = wf1 + (size_t)l * EE * FFH;
        int r = idx >> 8, c = idx & 255;
        dst[262144 + idx] = f2bf(src[(size_t)c * FFH + r]);
    } else {
        if (idx >= EE * FFH) return;
        const float* src = wf2 + (size_t)l * FFH * EE;
        int r = idx >> 9, c = idx & 511;
        dst[393216 + idx] = f2bf(src[(size_t)c * EE + r]);
    }
}

// ---------- embed (segment version): 32 tokens/block, w2 col in regs ----------
template<int IND, int SEG, int G0>
__global__ __launch_bounds__(256) void embed_seg(
    const float* __restrict__ obs,
    const float* __restrict__ w1, const float* __restrict__ b1,
    const float* __restrict__ w2, const float* __restrict__ b2,
    float* __restrict__ h, u16* __restrict__ hb)
{
    __shared__ float xs[32][9];
    __shared__ float hid[32][33];
    int t = threadIdx.x;
    int fi0 = blockIdx.x * 32;

    for (int p = t; p < 32 * 9; p += 256) {
        int tok = p / 9, f = p % 9;
        int fi = fi0 + tok;
        int b = fi / SEG, g = G0 + fi % SEG;
        xs[tok][f] = obs[((size_t)b * GG + g) * 9 + f];
    }
    __syncthreads();

    #pragma unroll
    for (int p = 0; p < 4; p++) {
        int idx = p * 256 + t;
        int tok = idx >> 5, hcol = idx & 31;
        float a = b1[hcol];
        #pragma unroll
        for (int i = 0; i < IND; i++) a += xs[tok][i] * w1[i * 32 + hcol];
        hid[tok][hcol] = (a > 0.0f) ? a : 0.01f * a;
    }
    __syncthreads();

    float w2c[32];
    #pragma unroll
    for (int j = 0; j < 32; j++) w2c[j] = w2[j * EE + t];
    float bb = b2[t];
    for (int tok = 0; tok < 32; tok++) {
        int fi = fi0 + tok;
        int b = fi / SEG, g = G0 + fi % SEG;
        float a = bb;
        #pragma unroll
        for (int j = 0; j < 32; j++) a += hid[tok][j] * w2c[j];
        size_t o = ((size_t)b * GP + g) * EE + t;
        h[o] = a; hb[o] = f2bf(a);
    }
}

// zero the pad rows g in [GG, GP)
__global__ __launch_bounds__(256) void pad_kernel(float* __restrict__ h, u16* __restrict__ hb)
{
    int b = blockIdx.x, t = threadIdx.x;
    for (int g = GG; g < GP; g++) {
        size_t o = ((size_t)b * GP + g) * EE + t;
        h[o] = 0.0f; hb[o] = 0;
    }
}

// --------- QKV GEMM: 128x128 tile, dbuf counted-vmcnt staging ---------
__global__ __launch_bounds__(256) void qkv_gemm(
    const u16* __restrict__ hb, const u16* __restrict__ wqkvT,
    u16* __restrict__ qb, u16* __restrict__ kb, u16* __restrict__ vt)
{
    __shared__ __align__(16) u16 sA[2][128 * 64];   // 2 x 16 KB
    __shared__ __align__(16) u16 sB[2][128 * 64];   // 2 x 16 KB
    int tid = threadIdx.x, lane = tid & 63, w = tid >> 6;
    int wm = w >> 1, wn = w & 1;
    int lr = lane & 15, q = lane >> 4;
    int brow = blockIdx.x * 128;
    int bcol = blockIdx.y * 128;

    f32x4 acc[4][4];
    #pragma unroll
    for (int i = 0; i < 4; i++)
        #pragma unroll
        for (int j = 0; j < 4; j++) acc[i][j] = {0.0f, 0.0f, 0.0f, 0.0f};

    stage_swz(hb + (size_t)brow * 256, 256, 0, sA[0], 16, w, 4, lane);
    stage_swz(wqkvT + (size_t)bcol * 256, 256, 0, sB[0], 16, w, 4, lane);

    for (int ks = 0; ks < 4; ks++) {
        int cur = ks & 1;
        if (ks < 3) {
            stage_swz(hb + (size_t)brow * 256, 256, (ks + 1) * 64, sA[cur ^ 1], 16, w, 4, lane);
            stage_swz(wqkvT + (size_t)bcol * 256, 256, (ks + 1) * 64, sB[cur ^ 1], 16, w, 4, lane);
            asm volatile("s_waitcnt vmcnt(8)" ::: "memory");
        } else {
            asm volatile("s_waitcnt vmcnt(0)" ::: "memory");
        }
        __builtin_amdgcn_s_barrier();
        #pragma unroll
        for (int kk = 0; kk < 2; kk++) {
            bf16x8 a[4], b[4];
            #pragma unroll
            for (int i = 0; i < 4; i++) {
                a[i] = lds_frag(sA[cur], wm * 64 + i * 16 + lr, kk, q);
                b[i] = lds_frag(sB[cur], wn * 64 + i * 16 + lr, kk, q);
            }
            #pragma unroll
            for (int mi = 0; mi < 4; mi++)
                #pragma unroll
                for (int ni = 0; ni < 4; ni++)
                    acc[mi][ni] = MFMA(a[mi], b[ni], acc[mi][ni]);
        }
        __builtin_amdgcn_sched_barrier(0);
        __builtin_amdgcn_s_barrier();
    }

    if (bcol < 512) {
        u16* dst = (bcol < 256) ? qb : kb;
        int cOff = bcol & 255;
        #pragma unroll
        for (int mi = 0; mi < 4; mi++)
            #pragma unroll
            for (int ni = 0; ni < 4; ni++) {
                int col = cOff + wn * 64 + ni * 16 + lr;
                #pragma unroll
                for (int j = 0; j < 4; j++) {
                    int rowG = brow + wm * 64 + mi * 16 + q * 4 + j;
                    dst[(size_t)rowG * 256 + col] = f2bf(acc[mi][ni][j]);
                }
            }
    } else {
        #pragma unroll
        for (int mi = 0; mi < 4; mi++) {
            int rowG0 = brow + wm * 64 + mi * 16 + q * 4;
            int b0 = rowG0 / GP;
            int g0 = rowG0 - b0 * GP;
            #pragma unroll
            for (int ni = 0; ni < 4; ni++) {
                int e = (bcol - 512) + wn * 64 + ni * 16 + lr;
                ushort4 u4;
                u4.x = f2bf(acc[mi][ni][0]);
                u4.y = f2bf(acc[mi][ni][1]);
                u4.z = f2bf(acc[mi][ni][2]);
                u4.w = f2bf(acc[mi][ni][3]);
                *(ushort4*)(vt + ((size_t)(b0 * EE + e)) * GP + g0) = u4;
            }
        }
    }
}

// --------- FF1 GEMM: 128x128 tile, dbuf, epilogue bias+relu -> hidb ---------
__global__ __launch_bounds__(256) void ff1_gemm(
    const u16* __restrict__ hb, const u16* __restrict__ w1T,
    const float* __restrict__ bf1, u16* __restrict__ hidb)
{
    __shared__ __align__(16) u16 sA[2][128 * 64];
    __shared__ __align__(16) u16 sB[2][128 * 64];
    int tid = threadIdx.x, lane = tid & 63, w = tid >> 6;
    int wm = w >> 1, wn = w & 1;
    int lr = lane & 15, q = lane >> 4;
    int brow = blockIdx.x * 128;
    int bcol = blockIdx.y * 128;

    f32x4 acc[4][4];
    #pragma unroll
    for (int i = 0; i < 4; i++)
        #pragma unroll
        for (int j = 0; j < 4; j++) acc[i][j] = {0.0f, 0.0f, 0.0f, 0.0f};

    stage_swz(hb + (size_t)brow * 256, 256, 0, sA[0], 16, w, 4, lane);
    stage_swz(w1T + (size_t)bcol * 256, 256, 0, sB[0], 16, w, 4, lane);

    for (int ks = 0; ks < 4; ks++) {
        int cur = ks & 1;
        if (ks < 3) {
            stage_swz(hb + (size_t)brow * 256, 256, (ks + 1) * 64, sA[cur ^ 1], 16, w, 4, lane);
            stage_swz(w1T + (size_t)bcol * 256, 256, (ks + 1) * 64, sB[cur ^ 1], 16, w, 4, lane);
            asm volatile("s_waitcnt vmcnt(8)" ::: "memory");
        } else {
            asm volatile("s_waitcnt vmcnt(0)" ::: "memory");
        }
        __builtin_amdgcn_s_barrier();
        #pragma unroll
        for (int kk = 0; kk < 2; kk++) {
            bf16x8 a[4], b[4];
            #pragma unroll
            for (int i = 0; i < 4; i++) {
                a[i] = lds_frag(sA[cur], wm * 64 + i * 16 + lr, kk, q);
                b[i] = lds_frag(sB[cur], wn * 64 + i * 16 + lr, kk, q);
            }
            #pragma unroll
            for (int mi = 0; mi < 4; mi++)
                #pragma unroll
                for (int ni = 0; ni < 4; ni++)
                    acc[mi][ni] = MFMA(a[mi], b[ni], acc[mi][ni]);
        }
        __builtin_amdgcn_sched_barrier(0);
        __builtin_amdgcn_s_barrier();
    }

    #pragma unroll
    for (int ni = 0; ni < 4; ni++) {
        int col = bcol + wn * 64 + ni * 16 + lr;
        float bias = bf1[col];
        #pragma unroll
        for (int mi = 0; mi < 4; mi++)
            #pragma unroll
            for (int j = 0; j < 4; j++) {
                int rowG = brow + wm * 64 + mi * 16 + q * 4 + j;
                float v = acc[mi][ni][j] + bias;
                hidb[(size_t)rowG * 512 + col] = f2bf(fmaxf(v, 0.0f));
            }
    }
}

// ---- GEMM + residual + LayerNorm: BM=64, BN=256(full row), 8 waves,
//      dbuf counted-vmcnt staging. STR = K = A-stride = B-stride. ----
template<int KSTEPS, int STR, bool HASB>
__global__ __launch_bounds__(512) void gemmln_kernel(
    const u16* __restrict__ A, const u16* __restrict__ Bw,
    const float* __restrict__ bias, float* __restrict__ h, u16* __restrict__ hb)
{
    __shared__ __align__(16) u16 sA[2][64 * 64];    // 2 x 8 KB
    __shared__ __align__(16) u16 sB[2][256 * 64];   // 2 x 32 KB
    int tid = threadIdx.x, lane = tid & 63, w = tid >> 6;
    int wm = w >> 2, wn = w & 3;
    int lr = lane & 15, q = lane >> 4;
    int brow = blockIdx.x * 64;

    f32x4 acc[2][4];
    #pragma unroll
    for (int i = 0; i < 2; i++)
        #pragma unroll
        for (int j = 0; j < 4; j++) acc[i][j] = {0.0f, 0.0f, 0.0f, 0.0f};

    stage_swz(A + (size_t)brow * STR, STR, 0, sA[0], 8, w, 8, lane);
    stage_swz(Bw, STR, 0, sB[0], 32, w, 8, lane);

    for (int ks = 0; ks < KSTEPS; ks++) {
        int cur = ks & 1;
        if (ks + 1 < KSTEPS) {
            stage_swz(A + (size_t)brow * STR, STR, (ks + 1) * 64, sA[cur ^ 1], 8, w, 8, lane);
            stage_swz(Bw, STR, (ks + 1) * 64, sB[cur ^ 1], 32, w, 8, lane);
            asm volatile("s_waitcnt vmcnt(5)" ::: "memory");
        } else {
            asm volatile("s_waitcnt vmcnt(0)" ::: "memory");
        }
        __builtin_amdgcn_s_barrier();
        #pragma unroll
        for (int kk = 0; kk < 2; kk++) {
            bf16x8 a[2], b[4];
            #pragma unroll
            for (int i = 0; i < 2; i++)
                a[i] = lds_frag(sA[cur], wm * 32 + i * 16 + lr, kk, q);
            #pragma unroll
            for (int n = 0; n < 4; n++)
                b[n] = lds_frag(sB[cur], wn * 64 + n * 16 + lr, kk, q);
            #pragma unroll
            for (int mi = 0; mi < 2; mi++)
                #pragma unroll
                for (int ni = 0; ni < 4; ni++)
                    acc[mi][ni] = MFMA(a[mi], b[ni], acc[mi][ni]);
        }
        __builtin_amdgcn_sched_barrier(0);
        __builtin_amdgcn_s_barrier();
    }

    __syncthreads();
    float* sPart = (float*)sA;           // [4 wn][64 row][2] = 2 KB

    #pragma unroll
    for (int ni = 0; ni < 4; ni++) {
        int col = wn * 64 + ni * 16 + lr;
        float bv = HASB ? bias[col] : 0.0f;
        #pragma unroll
        for (int mi = 0; mi < 2; mi++)
            #pragma unroll
            for (int j = 0; j < 4; j++) {
                int rowG = brow + wm * 32 + mi * 16 + q * 4 + j;
                acc[mi][ni][j] += bv + h[(size_t)rowG * 256 + col];
            }
    }
    #pragma unroll
    for (int mi = 0; mi < 2; mi++)
        #pragma unroll
        for (int j = 0; j < 4; j++) {
            float s1 = 0.0f, s2 = 0.0f;
            #pragma unroll
            for (int ni = 0; ni < 4; ni++) {
                float v = acc[mi][ni][j];
                s1 += v; s2 += v * v;
            }
            s1 += __shfl_xor(s1, 1); s2 += __shfl_xor(s2, 1);
            s1 += __shfl_xor(s1, 2); s2 += __shfl_xor(s2, 2);
            s1 += __shfl_xor(s1, 4); s2 += __shfl_xor(s2, 4);
            s1 += __shfl_xor(s1, 8); s2 += __shfl_xor(s2, 8);
            if (lr == 0) {
                int lrow = wm * 32 + mi * 16 + q * 4 + j;
                sPart[(wn * 64 + lrow) * 2 + 0] = s1;
                sPart[(wn * 64 + lrow) * 2 + 1] = s2;
            }
        }
    __syncthreads();

    #pragma unroll
    for (int mi = 0; mi < 2; mi++)
        #pragma unroll
        for (int j = 0; j < 4; j++) {
            int lrow = wm * 32 + mi * 16 + q * 4 + j;
            float s1 = sPart[lrow * 2] + sPart[(64 + lrow) * 2] +
                       sPart[(128 + lrow) * 2] + sPart[(192 + lrow) * 2];
            float s2 = sPart[lrow * 2 + 1] + sPart[(64 + lrow) * 2 + 1] +
                       sPart[(128 + lrow) * 2 + 1] + sPart[(192 + lrow) * 2 + 1];
            float mean = s1 * (1.0f / 256.0f);
            float var  = s2 * (1.0f / 256.0f) - mean * mean;
            float rstd = rsqrtf(var + 1e-5f);
            int rowG = brow + lrow;
            #pragma unroll
            for (int ni = 0; ni < 4; ni++) {
                int col = wn * 64 + ni * 16 + lr;
                float v = (acc[mi][ni][j] - mean) * rstd;
                size_t o = (size_t)rowG * 256 + col;
                h[o] = v; hb[o] = f2bf(v);
            }
        }
}

// ------- attention core (flash-LDS): K/V staged via global_load_lds with
// counted-vmcnt prefetch; two-pass softmax; P in LDS (stride 344, ~2-way).
// 64 q-rows/block, 512 thr (8 waves: wm row-quarter, wn j/e-half).
// XCD-bijective swizzle keeps a batch's K/V on one XCD's L2.
// aob may alias qb: Q read into regs at block start, aob written at end,
// both only this block's own 64 rows.
__global__ __launch_bounds__(512) void attn_core(
    const u16* __restrict__ qb, const u16* __restrict__ kb,
    const u16* __restrict__ vt, const float* __restrict__ obs,
    u16* __restrict__ aob)
{
    __shared__ __align__(16) u16 sKV[2][16384];   // 64 KB: K tiles, then V tiles
    __shared__ __align__(16) u16 sP[64 * 344];    // 43 KB, stride 344 (2-way banks)
    __shared__ float sBias[320];
    __shared__ float sPm[2][64], sPs[2][64];

    int id = blockIdx.x;                 // 1280 blocks
    int xcd = id & 7, jj = id >> 3;      // jj in [0,160)
    int tile = jj % 5, bgrp = jj / 5;    // bgrp in [0,32)
    int b = xcd + 8 * bgrp;              // bijective batch
    int t0 = tile * 64;

    int tid = threadIdx.x, w = tid >> 6, lane = tid & 63;
    int wm = w >> 1, wn = w & 1;         // row-quarter (16 rows), j/e-half
    int lr = lane & 15, q = lane >> 4, lk = q * 8;

    if (tid < 320) {
        float msk = (tid < GG) ? obs[((size_t)b * GG + tid) * 9 + 8] : 0.0f;
        sBias[tid] = (1.0f - msk) * -1e9f;
    }

    // Q fragments for this wave's 16 rows: 8 x bf16x8 (all 256 k)
    const u16* qbase = qb + ((size_t)(b * GP + t0 + wm * 16 + lr)) * 256;
    bf16x8 af[8];
    #pragma unroll
    for (int k8 = 0; k8 < 8; k8++) af[k8] = *(const bf16x8*)(qbase + k8 * 32 + lk);

    const u16* vbase = vt + (size_t)b * EE * GP;

    // ---- scores: 5 K-tiles of 64 keys, double-buffered, counted vmcnt ----
    #pragma unroll
    for (int r = 0; r < 4; r++)
        stage_swz(kb + ((size_t)b * GP) * 256, 256, r * 64, sKV[0] + r * 4096, 8, w, 8, lane);

    f32x4 sacc[10];
    #pragma unroll
    for (int s = 0; s < 10; s++) sacc[s] = {0.0f, 0.0f, 0.0f, 0.0f};

    for (int t = 0; t < 5; t++) {
        if (t < 4) {
            #pragma unroll
            for (int r = 0; r < 4; r++)
                stage_swz(kb + ((size_t)(b * GP + (t + 1) * 64)) * 256, 256, r * 64,
                          sKV[(t + 1) & 1] + r * 4096, 8, w, 8, lane);
            asm volatile("s_waitcnt vmcnt(4)" ::: "memory");
        } else {
            asm volatile("s_waitcnt vmcnt(0)" ::: "memory");
        }
        __builtin_amdgcn_s_barrier();
        const u16* kbuf = sKV[t & 1];
        #pragma unroll
        for (int ks = 0; ks < 4; ks++)
            #pragma unroll
            for (int kk = 0; kk < 2; kk++) {
                bf16x8 a = af[ks * 2 + kk];
                #pragma unroll
                for (int l = 0; l < 2; l++) {
                    int jl = (wn * 2 + l) * 16 + lr;
                    bf16x8 bb = lds_frag(kbuf + ks * 4096, jl, kk, q);
                    sacc[t * 2 + l] = MFMA(a, bb, sacc[t * 2 + l]);
                }
            }
        __builtin_amdgcn_s_barrier();
    }

    // ---- bias + softmax (two partials over wn) ----
    #pragma unroll
    for (int s = 0; s < 10; s++) {
        int j = (s >> 1) * 64 + (wn * 2 + (s & 1)) * 16 + lr;
        float bia = sBias[j];
        #pragma unroll
        for (int r = 0; r < 4; r++) sacc[s][r] = sacc[s][r] * 0.0625f + bia;
    }
    #pragma unroll
    for (int r = 0; r < 4; r++) {
        float mx = -1e30f;
        #pragma unroll
        for (int s = 0; s < 10; s++) mx = fmaxf(mx, sacc[s][r]);
        mx = fmaxf(mx, __shfl_xor(mx, 1));
        mx = fmaxf(mx, __shfl_xor(mx, 2));
        mx = fmaxf(mx, __shfl_xor(mx, 4));
        mx = fmaxf(mx, __shfl_xor(mx, 8));
        if (lr == 0) sPm[wn][wm * 16 + q * 4 + r] = mx;
    }
    __syncthreads();

    // prefetch V0 into buf0 (K compute fully done); softmax hides its latency
    stage_swz(vbase, GP, 0 * 64, sKV[0], 32, w, 8, lane);

    #pragma unroll
    for (int r = 0; r < 4; r++) {
        int row = wm * 16 + q * 4 + r;
        float rm = fmaxf(sPm[0][row], sPm[1][row]);
        float ss = 0.0f;
        #pragma unroll
        for (int s = 0; s < 10; s++) {
            float e = __expf(sacc[s][r] - rm);
            sacc[s][r] = e;
            ss += e;
        }
        ss += __shfl_xor(ss, 1);
        ss += __shfl_xor(ss, 2);
        ss += __shfl_xor(ss, 4);
        ss += __shfl_xor(ss, 8);
        if (lr == 0) sPs[wn][row] = ss;
    }
    __syncthreads();
    #pragma unroll
    for (int r = 0; r < 4; r++) {
        int row = wm * 16 + q * 4 + r;
        float inv = 1.0f / (sPs[0][row] + sPs[1][row]);
        #pragma unroll
        for (int s = 0; s < 10; s++) {
            int j = (s >> 1) * 64 + (wn * 2 + (s & 1)) * 16 + lr;
            sP[row * 344 + j] = f2bf(sacc[s][r] * inv);
        }
    }
    __syncthreads();

    // ---- PV: 5 V-tiles of 64 keys (V^T [256 e][64 g]), double-buffered ----
    f32x4 oacc[8];
    #pragma unroll
    for (int n = 0; n < 8; n++) oacc[n] = {0.0f, 0.0f, 0.0f, 0.0f};

    for (int c = 0; c < 5; c++) {
        if (c < 4) {
            stage_swz(vbase, GP, (c + 1) * 64, sKV[(c + 1) & 1], 32, w, 8, lane);
            asm volatile("s_waitcnt vmcnt(4)" ::: "memory");
        } else {
            asm volatile("s_waitcnt vmcnt(0)" ::: "memory");
        }
        __builtin_amdgcn_s_barrier();
        const u16* vbuf = sKV[c & 1];
        #pragma unroll
        for (int kk = 0; kk < 2; kk++) {
            bf16x8 a = *(const bf16x8*)(sP + (wm * 16 + lr) * 344 + c * 64 + kk * 32 + lk);
            #pragma unroll
            for (int n = 0; n < 8; n++) {
                bf16x8 vv = lds_frag(vbuf, wn * 128 + n * 16 + lr, kk, q);
                oacc[n] = MFMA(a, vv, oacc[n]);
            }
        }
        __builtin_amdgcn_s_barrier();
    }

    #pragma unroll
    for (int n = 0; n < 8; n++) {
        int col = wn * 128 + n * 16 + lr;
        #pragma unroll
        for (int r = 0; r < 4; r++) {
            int row = wm * 16 + q * 4 + r;
            aob[((size_t)(b * GP + t0 + row)) * 256 + col] = f2bf(oacc[n][r]);
        }
    }
}

// ------------- head part 1: graph embed -> fixed context -> u[b] -------------
__global__ __launch_bounds__(256) void final1_kernel(
    const float* __restrict__ h, const float* __restrict__ obs,
    const float* __restrict__ w_fc, const float* __restrict__ w_pn,
    float* __restrict__ u)
{
    int b = blockIdx.x;
    int t = threadIdx.x;
    __shared__ float ges[EE];
    __shared__ float fcs[EE];

    float acc = 0.0f, vlen = 0.0f;
    for (int g = 0; g < GG; g++) {
        float m = obs[((size_t)b * GG + g) * 9 + 8];
        vlen += m;
        acc += h[((size_t)b * GP + g) * EE + t] * m;
    }
    ges[t] = acc / vlen;
    __syncthreads();

    float fc = 0.0f;
    for (int kk = 0; kk < EE; kk++) fc += ges[kk] * w_fc[kk * EE + t];
    fcs[t] = fc;
    __syncthreads();

    const float4* wp = reinterpret_cast<const float4*>(w_pn + (size_t)t * 3 * EE);
    float ua = 0.0f;
    for (int kk = 0; kk < EE / 4; kk++) {
        float4 w = wp[kk];
        ua += w.x * fcs[kk * 4] + w.y * fcs[kk * 4 + 1] +
              w.z * fcs[kk * 4 + 2] + w.w * fcs[kk * 4 + 3];
    }
    u[(size_t)b * EE + t] = ua;
}

// ------------- head part 2: compat -> tanh clip -> masked softmax -------------
__global__ __launch_bounds__(128) void final2_kernel(
    const float* __restrict__ h, const float* __restrict__ obs,
    const float* __restrict__ u, float* __restrict__ out)
{
    int b = blockIdx.x;
    int t = threadIdx.x;
    __shared__ float us[EE];
    __shared__ float red[8];
    us[t]       = u[(size_t)b * EE + t];
    us[t + 128] = u[(size_t)b * EE + t + 128];
    __syncthreads();

    float logit = -INFINITY;
    float m = 0.0f;
    if (t < LHN) {
        int g = IHN + t;
        m = obs[((size_t)b * GG + g) * 9 + 8];
        const float4* hr = reinterpret_cast<const float4*>(h + ((size_t)b * GP + g) * EE);
        float c = 0.0f;
        for (int kk = 0; kk < EE / 4; kk++) {
            float4 hv = hr[kk];
            c += hv.x * us[kk * 4] + hv.y * us[kk * 4 + 1] +
                 hv.z * us[kk * 4 + 2] + hv.w * us[kk * 4 + 3];
        }
        c *= m;
        c *= 0.0625f;
        logit = tanhf(c) * 10.0f;
    }
    float bm = blockReduceMax(logit, red);
    float e  = (t < LHN) ? __expf(logit - bm) : 0.0f;
    float bs = blockReduceSum(e, red);
    float p  = e / bs;
    float masked = (t < LHN) ? (p * m + 1e-20f) : 0.0f;
    float bs2 = blockReduceSum(masked, red);
    if (t < LHN) out[(size_t)b * LHN + t] = masked / bs2;
}

extern "C" void kernel_launch(void* const* d_in, const int* in_sizes, int n_in,
                              void* d_out, int out_size, void* d_ws, size_t ws_size,
                              hipStream_t stream) {
    const float* obs   = (const float*)d_in[0];
    const float* wi1   = (const float*)d_in[1];
    const float* bi1   = (const float*)d_in[2];
    const float* wi2   = (const float*)d_in[3];
    const float* bi2   = (const float*)d_in[4];
    const float* wl1   = (const float*)d_in[5];
    const float* bl1   = (const float*)d_in[6];
    const float* wl2   = (const float*)d_in[7];
    const float* bl2   = (const float*)d_in[8];
    const float* wn1   = (const float*)d_in[9];
    const float* bn1   = (const float*)d_in[10];
    const float* wn2   = (const float*)d_in[11];
    const float* bn2   = (const float*)d_in[12];
    const float* e_wq  = (const float*)d_in[13];
    const float* e_wk  = (const float*)d_in[14];
    const float* e_wv  = (const float*)d_in[15];
    const float* e_wo  = (const float*)d_in[16];
    const float* e_wf1 = (const float*)d_in[17];
    const float* e_bf1 = (const float*)d_in[18];
    const float* e_wf2 = (const float*)d_in[19];
    const float* e_bf2 = (const float*)d_in[20];
    const float* w_pn  = (const float*)d_in[21];
    const float* w_fc  = (const float*)d_in[22];
    float* outp = (float*)d_out;

    // ---- compact workspace layout: 254,017,536 B total ----
    char* wsc = (char*)d_ws;
    float* h    = (float*)wsc;
    u16*   hb   = (u16*)(wsc + 83886080);
    u16*   qaob = (u16*)(wsc + 125829120);   // qb, later aob
    u16*   kb   = (u16*)(wsc + 167772160);
    u16*   vt   = (u16*)(wsc + 209715200);
    u16*   wT   = (u16*)(wsc + 251658240);
    float* ubuf = (float*)(wsc + 253755392);
    u16*   hidb = kb;  // overlays kb+vt (disjoint lifetime)

    prep_kernel<<<dim3(512, 12), 256, 0, stream>>>(e_wq, e_wk, e_wv, e_wo, e_wf1, e_wf2, wT);
    pad_kernel<<<BB, 256, 0, stream>>>(h, hb);
    embed_seg<ILN, IHN, 0><<<IHN * BB / 32, 256, 0, stream>>>(obs, wi1, bi1, wi2, bi2, h, hb);
    embed_seg<8, LHN, IHN><<<LHN * BB / 32, 256, 0, stream>>>(obs, wl1, bl1, wl2, bl2, h, hb);
    embed_seg<6, 1, IHN + LHN><<<BB / 32, 256, 0, stream>>>(obs, wn1, bn1, wn2, bn2, h, hb);

    const size_t WL = 524288;
    for (int l = 0; l < NL; l++) {
        u16* wqkvT = wT + l * WL;
        u16* woT   = wqkvT + 196608;
        u16* w1T   = wqkvT + 262144;
        u16* w2T   = wqkvT + 393216;
        const float* bf1 = e_bf1 + (size_t)l * FFH;
        const float* bf2 = e_bf2 + (size_t)l * EE;

        qkv_gemm<<<dim3(MT / 128, 6), 256, 0, stream>>>(hb, wqkvT, qaob, kb, vt);
        attn_core<<<1280, 512, 0, stream>>>(qaob, kb, vt, obs, qaob);
        gemmln_kernel<4, 256, false><<<MT / 64, 512, 0, stream>>>(qaob, woT, nullptr, h, hb);
        ff1_gemm<<<dim3(MT / 128, 4), 256, 0, stream>>>(hb, w1T, bf1, hidb);
        gemmln_kernel<8, 512, true><<<MT / 64, 512, 0, stream>>>(hidb, w2T, bf2, h, hb);
    }
    final1_kernel<<<BB, 256, 0, stream>>>(h, obs, w_fc, w_pn, ubuf);
    final2_kernel<<<BB, 128, 0, stream>>>(h, obs, ubuf, outp);
}

// Round 11
// 700.298 us; speedup vs baseline: 1.4605x; 1.0151x over previous
//
#include <hip/hip_runtime.h>
#include <math.h>

static constexpr int BB   = 256;   // batch
static constexpr int IHN  = 200;   // internal tokens
static constexpr int ILN  = 6;     // internal feature dim
static constexpr int LHN  = 100;   // leaf tokens
static constexpr int EE   = 256;   // embed dim
static constexpr int FFH  = 512;   // ff hidden
static constexpr int NL   = 2;     // layers
static constexpr int GG   = 301;   // real tokens
static constexpr int GP   = 320;   // padded tokens (10 x 32)
static constexpr int MT   = BB * GP;  // 81920 total token rows

typedef unsigned short u16;
typedef short bf16x8 __attribute__((ext_vector_type(8)));
typedef float f32x4 __attribute__((ext_vector_type(4)));

#define MFMA(a, b, c) __builtin_amdgcn_mfma_f32_16x16x32_bf16((a), (b), (c), 0, 0, 0)

__device__ __forceinline__ u16 f2bf(float f) {
    union { float f; unsigned u; } v; v.f = f;
    unsigned r = v.u + 0x7FFFu + ((v.u >> 16) & 1u);
    return (u16)(r >> 16);
}

// ---------------- wave/block reduction helpers (wave = 64) ----------------
__device__ __forceinline__ float waveReduceSum(float v) {
    for (int o = 32; o > 0; o >>= 1) v += __shfl_down(v, o, 64);
    return v;
}
__device__ __forceinline__ float waveReduceMax(float v) {
    for (int o = 32; o > 0; o >>= 1) v = fmaxf(v, __shfl_down(v, o, 64));
    return v;
}
__device__ __forceinline__ float blockReduceSum(float v, float* red) {
    int lane = threadIdx.x & 63;
    int w    = threadIdx.x >> 6;
    int nw   = (blockDim.x + 63) >> 6;
    v = waveReduceSum(v);
    if (lane == 0) red[w] = v;
    __syncthreads();
    if (threadIdx.x < 64) {
        float x = (lane < nw) ? red[lane] : 0.0f;
        x = waveReduceSum(x);
        if (lane == 0) red[0] = x;
    }
    __syncthreads();
    float r = red[0];
    __syncthreads();
    return r;
}
__device__ __forceinline__ float blockReduceMax(float v, float* red) {
    int lane = threadIdx.x & 63;
    int w    = threadIdx.x >> 6;
    int nw   = (blockDim.x + 63) >> 6;
    v = waveReduceMax(v);
    if (lane == 0) red[w] = v;
    __syncthreads();
    if (threadIdx.x < 64) {
        float x = (lane < nw) ? red[lane] : -INFINITY;
        x = waveReduceMax(x);
        if (lane == 0) red[0] = x;
    }
    __syncthreads();
    float r = red[0];
    __syncthreads();
    return r;
}

// --------- staging: global -> LDS tile [rows][64] bf16, XOR-swizzled ---------
__device__ __forceinline__ void stage_swz(const u16* src, int strideShorts, int k0,
                                          u16* ldsTile, int nChunks, int wave,
                                          int nWaves, int lane)
{
    for (int c = wave; c < nChunks; c += nWaves) {
        int o = c * 1024 + lane * 16;
        int row = o >> 7;
        int cb = (o & 127) ^ ((row & 7) << 4);
        const u16* g = src + (size_t)row * strideShorts + k0 + (cb >> 1);
        __builtin_amdgcn_global_load_lds(
            (const __attribute__((address_space(1))) unsigned int*)g,
            (__attribute__((address_space(3))) unsigned int*)((char*)ldsTile + c * 1024),
            16, 0, 0);
    }
}

__device__ __forceinline__ bf16x8 lds_frag(const u16* tile, int row, int kk, int q)
{
    int cb = (kk * 64 + q * 16) ^ ((row & 7) << 4);
    return *(const bf16x8*)((const char*)tile + row * 128 + cb);
}

// ------------- prep: transpose encoder weights to bf16 [N][K] -------------
__global__ __launch_bounds__(256) void prep_kernel(
    const float* __restrict__ wq, const float* __restrict__ wk,
    const float* __restrict__ wv, const float* __restrict__ wo,
    const float* __restrict__ wf1, const float* __restrict__ wf2,
    u16* __restrict__ wT)
{
    int l = blockIdx.y / 6, m = blockIdx.y % 6;
    int idx = blockIdx.x * 256 + threadIdx.x;
    u16* dst = wT + (size_t)l * 524288;
    if (m < 4) {
        if (idx >= EE * EE) return;
        const float* src = (m == 0 ? wq : m == 1 ? wk : m == 2 ? wv : wo) + (size_t)l * EE * EE;
        int r = idx >> 8, c = idx & 255;
        dst[m * 65536 + idx] = f2bf(src[(size_t)c * EE + r]);
    } else if (m == 4) {
        if (idx >= FFH * EE) return;
        const float* src = wf1 + (size_t)l * EE * FFH;
        int r = idx >> 8, c = idx & 255;
        dst[262144 + idx] = f2bf(src[(size_t)c * FFH + r]);
    } else {
        if (idx >= EE * FFH) return;
        const float* src = wf2 + (size_t)l * FFH * EE;
        int r = idx >> 9, c = idx & 511;
        dst[393216 + idx] = f2bf(src[(size_t)c * EE + r]);
    }
}

// ---------- embed (segment version): 32 tokens/block, w2 col in regs ----------
template<int IND, int SEG, int G0>
__global__ __launch_bounds__(256) void embed_seg(
    const float* __restrict__ obs,
    const float* __restrict__ w1, const float* __restrict__ b1,
    const float* __restrict__ w2, const float* __restrict__ b2,
    float* __restrict__ h, u16* __restrict__ hb)
{
    __shared__ float xs[32][9];
    __shared__ float hid[32][33];
    int t = threadIdx.x;
    int fi0 = blockIdx.x * 32;

    for (int p = t; p < 32 * 9; p += 256) {
        int tok = p / 9, f = p % 9;
        int fi = fi0 + tok;
        int b = fi / SEG, g = G0 + fi % SEG;
        xs[tok][f] = obs[((size_t)b * GG + g) * 9 + f];
    }
    __syncthreads();

    #pragma unroll
    for (int p = 0; p < 4; p++) {
        int idx = p * 256 + t;
        int tok = idx >> 5, hcol = idx & 31;
        float a = b1[hcol];
        #pragma unroll
        for (int i = 0; i < IND; i++) a += xs[tok][i] * w1[i * 32 + hcol];
        hid[tok][hcol] = (a > 0.0f) ? a : 0.01f * a;
    }
    __syncthreads();

    float w2c[32];
    #pragma unroll
    for (int j = 0; j < 32; j++) w2c[j] = w2[j * EE + t];
    float bb = b2[t];
    for (int tok = 0; tok < 32; tok++) {
        int fi = fi0 + tok;
        int b = fi / SEG, g = G0 + fi % SEG;
        float a = bb;
        #pragma unroll
        for (int j = 0; j < 32; j++) a += hid[tok][j] * w2c[j];
        size_t o = ((size_t)b * GP + g) * EE + t;
        h[o] = a; hb[o] = f2bf(a);
    }
}

// zero the pad rows g in [GG, GP)
__global__ __launch_bounds__(256) void pad_kernel(float* __restrict__ h, u16* __restrict__ hb)
{
    int b = blockIdx.x, t = threadIdx.x;
    for (int g = GG; g < GP; g++) {
        size_t o = ((size_t)b * GP + g) * EE + t;
        h[o] = 0.0f; hb[o] = 0;
    }
}

// --------- QKV GEMM: 128x128 tile, dbuf counted-vmcnt staging ---------
__global__ __launch_bounds__(256) void qkv_gemm(
    const u16* __restrict__ hb, const u16* __restrict__ wqkvT,
    u16* __restrict__ qb, u16* __restrict__ kb, u16* __restrict__ vt)
{
    __shared__ __align__(16) u16 sA[2][128 * 64];   // 2 x 16 KB
    __shared__ __align__(16) u16 sB[2][128 * 64];   // 2 x 16 KB
    int tid = threadIdx.x, lane = tid & 63, w = tid >> 6;
    int wm = w >> 1, wn = w & 1;
    int lr = lane & 15, q = lane >> 4;
    int brow = blockIdx.x * 128;
    int bcol = blockIdx.y * 128;

    f32x4 acc[4][4];
    #pragma unroll
    for (int i = 0; i < 4; i++)
        #pragma unroll
        for (int j = 0; j < 4; j++) acc[i][j] = {0.0f, 0.0f, 0.0f, 0.0f};

    stage_swz(hb + (size_t)brow * 256, 256, 0, sA[0], 16, w, 4, lane);
    stage_swz(wqkvT + (size_t)bcol * 256, 256, 0, sB[0], 16, w, 4, lane);

    for (int ks = 0; ks < 4; ks++) {
        int cur = ks & 1;
        if (ks < 3) {
            stage_swz(hb + (size_t)brow * 256, 256, (ks + 1) * 64, sA[cur ^ 1], 16, w, 4, lane);
            stage_swz(wqkvT + (size_t)bcol * 256, 256, (ks + 1) * 64, sB[cur ^ 1], 16, w, 4, lane);
            asm volatile("s_waitcnt vmcnt(8)" ::: "memory");
        } else {
            asm volatile("s_waitcnt vmcnt(0)" ::: "memory");
        }
        __builtin_amdgcn_s_barrier();
        #pragma unroll
        for (int kk = 0; kk < 2; kk++) {
            bf16x8 a[4], b[4];
            #pragma unroll
            for (int i = 0; i < 4; i++) {
                a[i] = lds_frag(sA[cur], wm * 64 + i * 16 + lr, kk, q);
                b[i] = lds_frag(sB[cur], wn * 64 + i * 16 + lr, kk, q);
            }
            #pragma unroll
            for (int mi = 0; mi < 4; mi++)
                #pragma unroll
                for (int ni = 0; ni < 4; ni++)
                    acc[mi][ni] = MFMA(a[mi], b[ni], acc[mi][ni]);
        }
        __builtin_amdgcn_sched_barrier(0);
        __builtin_amdgcn_s_barrier();
    }

    if (bcol < 512) {
        u16* dst = (bcol < 256) ? qb : kb;
        int cOff = bcol & 255;
        #pragma unroll
        for (int mi = 0; mi < 4; mi++)
            #pragma unroll
            for (int ni = 0; ni < 4; ni++) {
                int col = cOff + wn * 64 + ni * 16 + lr;
                #pragma unroll
                for (int j = 0; j < 4; j++) {
                    int rowG = brow + wm * 64 + mi * 16 + q * 4 + j;
                    dst[(size_t)rowG * 256 + col] = f2bf(acc[mi][ni][j]);
                }
            }
    } else {
        #pragma unroll
        for (int mi = 0; mi < 4; mi++) {
            int rowG0 = brow + wm * 64 + mi * 16 + q * 4;
            int b0 = rowG0 / GP;
            int g0 = rowG0 - b0 * GP;
            #pragma unroll
            for (int ni = 0; ni < 4; ni++) {
                int e = (bcol - 512) + wn * 64 + ni * 16 + lr;
                ushort4 u4;
                u4.x = f2bf(acc[mi][ni][0]);
                u4.y = f2bf(acc[mi][ni][1]);
                u4.z = f2bf(acc[mi][ni][2]);
                u4.w = f2bf(acc[mi][ni][3]);
                *(ushort4*)(vt + ((size_t)(b0 * EE + e)) * GP + g0) = u4;
            }
        }
    }
}

// --------- FF1 GEMM: 128x128 tile, dbuf, epilogue bias+relu -> hidb ---------
__global__ __launch_bounds__(256) void ff1_gemm(
    const u16* __restrict__ hb, const u16* __restrict__ w1T,
    const float* __restrict__ bf1, u16* __restrict__ hidb)
{
    __shared__ __align__(16) u16 sA[2][128 * 64];
    __shared__ __align__(16) u16 sB[2][128 * 64];
    int tid = threadIdx.x, lane = tid & 63, w = tid >> 6;
    int wm = w >> 1, wn = w & 1;
    int lr = lane & 15, q = lane >> 4;
    int brow = blockIdx.x * 128;
    int bcol = blockIdx.y * 128;

    f32x4 acc[4][4];
    #pragma unroll
    for (int i = 0; i < 4; i++)
        #pragma unroll
        for (int j = 0; j < 4; j++) acc[i][j] = {0.0f, 0.0f, 0.0f, 0.0f};

    stage_swz(hb + (size_t)brow * 256, 256, 0, sA[0], 16, w, 4, lane);
    stage_swz(w1T + (size_t)bcol * 256, 256, 0, sB[0], 16, w, 4, lane);

    for (int ks = 0; ks < 4; ks++) {
        int cur = ks & 1;
        if (ks < 3) {
            stage_swz(hb + (size_t)brow * 256, 256, (ks + 1) * 64, sA[cur ^ 1], 16, w, 4, lane);
            stage_swz(w1T + (size_t)bcol * 256, 256, (ks + 1) * 64, sB[cur ^ 1], 16, w, 4, lane);
            asm volatile("s_waitcnt vmcnt(8)" ::: "memory");
        } else {
            asm volatile("s_waitcnt vmcnt(0)" ::: "memory");
        }
        __builtin_amdgcn_s_barrier();
        #pragma unroll
        for (int kk = 0; kk < 2; kk++) {
            bf16x8 a[4], b[4];
            #pragma unroll
            for (int i = 0; i < 4; i++) {
                a[i] = lds_frag(sA[cur], wm * 64 + i * 16 + lr, kk, q);
                b[i] = lds_frag(sB[cur], wn * 64 + i * 16 + lr, kk, q);
            }
            #pragma unroll
            for (int mi = 0; mi < 4; mi++)
                #pragma unroll
                for (int ni = 0; ni < 4; ni++)
                    acc[mi][ni] = MFMA(a[mi], b[ni], acc[mi][ni]);
        }
        __builtin_amdgcn_sched_barrier(0);
        __builtin_amdgcn_s_barrier();
    }

    #pragma unroll
    for (int ni = 0; ni < 4; ni++) {
        int col = bcol + wn * 64 + ni * 16 + lr;
        float bias = bf1[col];
        #pragma unroll
        for (int mi = 0; mi < 4; mi++)
            #pragma unroll
            for (int j = 0; j < 4; j++) {
                int rowG = brow + wm * 64 + mi * 16 + q * 4 + j;
                float v = acc[mi][ni][j] + bias;
                hidb[(size_t)rowG * 512 + col] = f2bf(fmaxf(v, 0.0f));
            }
    }
}

// ---- GEMM + residual + LayerNorm: BM=64, BN=256(full row), 8 waves,
//      dbuf counted-vmcnt staging. STR = K = A-stride = B-stride. ----
template<int KSTEPS, int STR, bool HASB>
__global__ __launch_bounds__(512) void gemmln_kernel(
    const u16* __restrict__ A, const u16* __restrict__ Bw,
    const float* __restrict__ bias, float* __restrict__ h, u16* __restrict__ hb)
{
    __shared__ __align__(16) u16 sA[2][64 * 64];    // 2 x 8 KB
    __shared__ __align__(16) u16 sB[2][256 * 64];   // 2 x 32 KB
    int tid = threadIdx.x, lane = tid & 63, w = tid >> 6;
    int wm = w >> 2, wn = w & 3;
    int lr = lane & 15, q = lane >> 4;
    int brow = blockIdx.x * 64;

    f32x4 acc[2][4];
    #pragma unroll
    for (int i = 0; i < 2; i++)
        #pragma unroll
        for (int j = 0; j < 4; j++) acc[i][j] = {0.0f, 0.0f, 0.0f, 0.0f};

    stage_swz(A + (size_t)brow * STR, STR, 0, sA[0], 8, w, 8, lane);
    stage_swz(Bw, STR, 0, sB[0], 32, w, 8, lane);

    for (int ks = 0; ks < KSTEPS; ks++) {
        int cur = ks & 1;
        if (ks + 1 < KSTEPS) {
            stage_swz(A + (size_t)brow * STR, STR, (ks + 1) * 64, sA[cur ^ 1], 8, w, 8, lane);
            stage_swz(Bw, STR, (ks + 1) * 64, sB[cur ^ 1], 32, w, 8, lane);
            asm volatile("s_waitcnt vmcnt(5)" ::: "memory");
        } else {
            asm volatile("s_waitcnt vmcnt(0)" ::: "memory");
        }
        __builtin_amdgcn_s_barrier();
        #pragma unroll
        for (int kk = 0; kk < 2; kk++) {
            bf16x8 a[2], b[4];
            #pragma unroll
            for (int i = 0; i < 2; i++)
                a[i] = lds_frag(sA[cur], wm * 32 + i * 16 + lr, kk, q);
            #pragma unroll
            for (int n = 0; n < 4; n++)
                b[n] = lds_frag(sB[cur], wn * 64 + n * 16 + lr, kk, q);
            #pragma unroll
            for (int mi = 0; mi < 2; mi++)
                #pragma unroll
                for (int ni = 0; ni < 4; ni++)
                    acc[mi][ni] = MFMA(a[mi], b[ni], acc[mi][ni]);
        }
        __builtin_amdgcn_sched_barrier(0);
        __builtin_amdgcn_s_barrier();
    }

    __syncthreads();
    float* sPart = (float*)sA;           // [4 wn][64 row][2] = 2 KB

    #pragma unroll
    for (int ni = 0; ni < 4; ni++) {
        int col = wn * 64 + ni * 16 + lr;
        float bv = HASB ? bias[col] : 0.0f;
        #pragma unroll
        for (int mi = 0; mi < 2; mi++)
            #pragma unroll
            for (int j = 0; j < 4; j++) {
                int rowG = brow + wm * 32 + mi * 16 + q * 4 + j;
                acc[mi][ni][j] += bv + h[(size_t)rowG * 256 + col];
            }
    }
    #pragma unroll
    for (int mi = 0; mi < 2; mi++)
        #pragma unroll
        for (int j = 0; j < 4; j++) {
            float s1 = 0.0f, s2 = 0.0f;
            #pragma unroll
            for (int ni = 0; ni < 4; ni++) {
                float v = acc[mi][ni][j];
                s1 += v; s2 += v * v;
            }
            s1 += __shfl_xor(s1, 1); s2 += __shfl_xor(s2, 1);
            s1 += __shfl_xor(s1, 2); s2 += __shfl_xor(s2, 2);
            s1 += __shfl_xor(s1, 4); s2 += __shfl_xor(s2, 4);
            s1 += __shfl_xor(s1, 8); s2 += __shfl_xor(s2, 8);
            if (lr == 0) {
                int lrow = wm * 32 + mi * 16 + q * 4 + j;
                sPart[(wn * 64 + lrow) * 2 + 0] = s1;
                sPart[(wn * 64 + lrow) * 2 + 1] = s2;
            }
        }
    __syncthreads();

    #pragma unroll
    for (int mi = 0; mi < 2; mi++)
        #pragma unroll
        for (int j = 0; j < 4; j++) {
            int lrow = wm * 32 + mi * 16 + q * 4 + j;
            float s1 = sPart[lrow * 2] + sPart[(64 + lrow) * 2] +
                       sPart[(128 + lrow) * 2] + sPart[(192 + lrow) * 2];
            float s2 = sPart[lrow * 2 + 1] + sPart[(64 + lrow) * 2 + 1] +
                       sPart[(128 + lrow) * 2 + 1] + sPart[(192 + lrow) * 2 + 1];
            float mean = s1 * (1.0f / 256.0f);
            float var  = s2 * (1.0f / 256.0f) - mean * mean;
            float rstd = rsqrtf(var + 1e-5f);
            int rowG = brow + lrow;
            #pragma unroll
            for (int ni = 0; ni < 4; ni++) {
                int col = wn * 64 + ni * 16 + lr;
                float v = (acc[mi][ni][j] - mean) * rstd;
                size_t o = (size_t)rowG * 256 + col;
                h[o] = v; hb[o] = f2bf(v);
            }
        }
}

// ------- attention core (flash-LDS, 2 blocks/CU): K/V staged via
// global_load_lds with counted-vmcnt prefetch; two-pass softmax; P kept
// packed-bf16 in REGISTERS and written per-tile to a single 9 KB LDS tile
// (stride 72 -> 2-way banks). LDS total ~77 KB -> 2 blocks/CU so one
// block's HBM-miss stalls hide under the other block's compute.
// 64 q-rows/block, 512 thr (8 waves: wm row-quarter, wn j/e-half).
// aob may alias qb: Q read into regs at block start, aob written at end.
__global__ __launch_bounds__(512) void attn_core(
    const u16* __restrict__ qb, const u16* __restrict__ kb,
    const u16* __restrict__ vt, const float* __restrict__ obs,
    u16* __restrict__ aob)
{
    __shared__ __align__(16) u16 sKV[2][16384];   // 64 KB: K tiles, then V tiles
    __shared__ __align__(16) u16 sPt[64 * 72];    // 9 KB: one 64-key P tile
    __shared__ float sBias[320];
    __shared__ float sPm[2][64], sPs[2][64];

    int id = blockIdx.x;                 // 1280 blocks
    int xcd = id & 7, jj = id >> 3;      // jj in [0,160)
    int tile = jj % 5, bgrp = jj / 5;    // bgrp in [0,32)
    int b = xcd + 8 * bgrp;              // bijective batch
    int t0 = tile * 64;

    int tid = threadIdx.x, w = tid >> 6, lane = tid & 63;
    int wm = w >> 1, wn = w & 1;         // row-quarter (16 rows), j/e-half
    int lr = lane & 15, q = lane >> 4, lk = q * 8;

    if (tid < 320) {
        float msk = (tid < GG) ? obs[((size_t)b * GG + tid) * 9 + 8] : 0.0f;
        sBias[tid] = (1.0f - msk) * -1e9f;
    }

    // Q fragments for this wave's 16 rows: 8 x bf16x8 (all 256 k)
    const u16* qbase = qb + ((size_t)(b * GP + t0 + wm * 16 + lr)) * 256;
    bf16x8 af[8];
    #pragma unroll
    for (int k8 = 0; k8 < 8; k8++) af[k8] = *(const bf16x8*)(qbase + k8 * 32 + lk);

    const u16* vbase = vt + (size_t)b * EE * GP;

    // ---- scores: 5 K-tiles of 64 keys, double-buffered, counted vmcnt ----
    #pragma unroll
    for (int r = 0; r < 4; r++)
        stage_swz(kb + ((size_t)b * GP) * 256, 256, r * 64, sKV[0] + r * 4096, 8, w, 8, lane);

    f32x4 sacc[10];
    #pragma unroll
    for (int s = 0; s < 10; s++) sacc[s] = {0.0f, 0.0f, 0.0f, 0.0f};

    #pragma unroll
    for (int t = 0; t < 5; t++) {
        if (t < 4) {
            #pragma unroll
            for (int r = 0; r < 4; r++)
                stage_swz(kb + ((size_t)(b * GP + (t + 1) * 64)) * 256, 256, r * 64,
                          sKV[(t + 1) & 1] + r * 4096, 8, w, 8, lane);
            asm volatile("s_waitcnt vmcnt(4)" ::: "memory");
        } else {
            asm volatile("s_waitcnt vmcnt(0)" ::: "memory");
        }
        __builtin_amdgcn_s_barrier();
        const u16* kbuf = sKV[t & 1];
        #pragma unroll
        for (int ks = 0; ks < 4; ks++)
            #pragma unroll
            for (int kk = 0; kk < 2; kk++) {
                bf16x8 a = af[ks * 2 + kk];
                #pragma unroll
                for (int l = 0; l < 2; l++) {
                    int jl = (wn * 2 + l) * 16 + lr;
                    bf16x8 bb = lds_frag(kbuf + ks * 4096, jl, kk, q);
                    sacc[t * 2 + l] = MFMA(a, bb, sacc[t * 2 + l]);
                }
            }
        __builtin_amdgcn_s_barrier();
    }

    // ---- bias + row max (two partials over wn) ----
    #pragma unroll
    for (int s = 0; s < 10; s++) {
        int j = (s >> 1) * 64 + (wn * 2 + (s & 1)) * 16 + lr;
        float bia = sBias[j];
        #pragma unroll
        for (int r = 0; r < 4; r++) sacc[s][r] = sacc[s][r] * 0.0625f + bia;
    }
    #pragma unroll
    for (int r = 0; r < 4; r++) {
        float mx = -1e30f;
        #pragma unroll
        for (int s = 0; s < 10; s++) mx = fmaxf(mx, sacc[s][r]);
        mx = fmaxf(mx, __shfl_xor(mx, 1));
        mx = fmaxf(mx, __shfl_xor(mx, 2));
        mx = fmaxf(mx, __shfl_xor(mx, 4));
        mx = fmaxf(mx, __shfl_xor(mx, 8));
        if (lr == 0) sPm[wn][wm * 16 + q * 4 + r] = mx;
    }
    __syncthreads();   // no vmem outstanding here (K loop drained to 0)

    // prefetch V0 into buf0 (K compute fully done); softmax hides its latency
    stage_swz(vbase, GP, 0 * 64, sKV[0], 32, w, 8, lane);

    #pragma unroll
    for (int r = 0; r < 4; r++) {
        int row = wm * 16 + q * 4 + r;
        float rm = fmaxf(sPm[0][row], sPm[1][row]);
        float ss = 0.0f;
        #pragma unroll
        for (int s = 0; s < 10; s++) {
            float e = __expf(sacc[s][r] - rm);
            sacc[s][r] = e;
            ss += e;
        }
        ss += __shfl_xor(ss, 1);
        ss += __shfl_xor(ss, 2);
        ss += __shfl_xor(ss, 4);
        ss += __shfl_xor(ss, 8);
        if (lr == 0) sPs[wn][row] = ss;
    }
    // lgkm-only barrier: must NOT drain vmcnt (V0 prefetch in flight)
    asm volatile("s_waitcnt lgkmcnt(0)" ::: "memory");
    __builtin_amdgcn_s_barrier();
    __builtin_amdgcn_sched_barrier(0);

    // ---- normalize + pack P to bf16 pairs in registers (frees sacc) ----
    float invr[4];
    #pragma unroll
    for (int r = 0; r < 4; r++) {
        int row = wm * 16 + q * 4 + r;
        invr[r] = 1.0f / (sPs[0][row] + sPs[1][row]);
    }
    unsigned pk[10][2];
    #pragma unroll
    for (int s = 0; s < 10; s++) {
        pk[s][0] = (unsigned)f2bf(sacc[s][0] * invr[0]) |
                   ((unsigned)f2bf(sacc[s][1] * invr[1]) << 16);
        pk[s][1] = (unsigned)f2bf(sacc[s][2] * invr[2]) |
                   ((unsigned)f2bf(sacc[s][3] * invr[3]) << 16);
    }

    // ---- PV: 5 V-tiles of 64 keys (V^T [256 e][64 g]), dbuf; P tile
    //      written from regs just-in-time into the single sPt buffer ----
    f32x4 oacc[8];
    #pragma unroll
    for (int n = 0; n < 8; n++) oacc[n] = {0.0f, 0.0f, 0.0f, 0.0f};

    #pragma unroll
    for (int c = 0; c < 5; c++) {
        if (c < 4) {
            stage_swz(vbase, GP, (c + 1) * 64, sKV[(c + 1) & 1], 32, w, 8, lane);
            asm volatile("s_waitcnt vmcnt(4)" ::: "memory");
        } else {
            asm volatile("s_waitcnt vmcnt(0)" ::: "memory");
        }
        __builtin_amdgcn_s_barrier();   // V_c ready; prev MFMA reads done; sPt free
        // write this tile's P slice (keys c*64..c*64+63)
        #pragma unroll
        for (int sl = 0; sl < 2; sl++) {
            int jl = (wn * 2 + sl) * 16 + lr;
            #pragma unroll
            for (int r = 0; r < 4; r++) {
                int row = wm * 16 + q * 4 + r;
                unsigned v = pk[c * 2 + sl][r >> 1];
                sPt[row * 72 + jl] = (u16)((r & 1) ? (v >> 16) : (v & 0xffffu));
            }
        }
        asm volatile("s_waitcnt lgkmcnt(0)" ::: "memory");
        __builtin_amdgcn_s_barrier();
        __builtin_amdgcn_sched_barrier(0);
        #pragma unroll
        for (int kk = 0; kk < 2; kk++) {
            bf16x8 a = *(const bf16x8*)(sPt + (wm * 16 + lr) * 72 + kk * 32 + lk);
            #pragma unroll
            for (int n = 0; n < 8; n++) {
                bf16x8 vv = lds_frag(sKV[c & 1], wn * 128 + n * 16 + lr, kk, q);
                oacc[n] = MFMA(a, vv, oacc[n]);
            }
        }
        __builtin_amdgcn_s_barrier();
    }

    #pragma unroll
    for (int n = 0; n < 8; n++) {
        int col = wn * 128 + n * 16 + lr;
        #pragma unroll
        for (int r = 0; r < 4; r++) {
            int row = wm * 16 + q * 4 + r;
            aob[((size_t)(b * GP + t0 + row)) * 256 + col] = f2bf(oacc[n][r]);
        }
    }
}

// ------------- head part 1: graph embed -> fixed context -> u[b] -------------
__global__ __launch_bounds__(256) void final1_kernel(
    const float* __restrict__ h, const float* __restrict__ obs,
    const float* __restrict__ w_fc, const float* __restrict__ w_pn,
    float* __restrict__ u)
{
    int b = blockIdx.x;
    int t = threadIdx.x;
    __shared__ float ges[EE];
    __shared__ float fcs[EE];

    float acc = 0.0f, vlen = 0.0f;
    for (int g = 0; g < GG; g++) {
        float m = obs[((size_t)b * GG + g) * 9 + 8];
        vlen += m;
        acc += h[((size_t)b * GP + g) * EE + t] * m;
    }
    ges[t] = acc / vlen;
    __syncthreads();

    float fc = 0.0f;
    for (int kk = 0; kk < EE; kk++) fc += ges[kk] * w_fc[kk * EE + t];
    fcs[t] = fc;
    __syncthreads();

    const float4* wp = reinterpret_cast<const float4*>(w_pn + (size_t)t * 3 * EE);
    float ua = 0.0f;
    for (int kk = 0; kk < EE / 4; kk++) {
        float4 w = wp[kk];
        ua += w.x * fcs[kk * 4] + w.y * fcs[kk * 4 + 1] +
              w.z * fcs[kk * 4 + 2] + w.w * fcs[kk * 4 + 3];
    }
    u[(size_t)b * EE + t] = ua;
}

// ------------- head part 2: compat -> tanh clip -> masked softmax -------------
__global__ __launch_bounds__(128) void final2_kernel(
    const float* __restrict__ h, const float* __restrict__ obs,
    const float* __restrict__ u, float* __restrict__ out)
{
    int b = blockIdx.x;
    int t = threadIdx.x;
    __shared__ float us[EE];
    __shared__ float red[8];
    us[t]       = u[(size_t)b * EE + t];
    us[t + 128] = u[(size_t)b * EE + t + 128];
    __syncthreads();

    float logit = -INFINITY;
    float m = 0.0f;
    if (t < LHN) {
        int g = IHN + t;
        m = obs[((size_t)b * GG + g) * 9 + 8];
        const float4* hr = reinterpret_cast<const float4*>(h + ((size_t)b * GP + g) * EE);
        float c = 0.0f;
        for (int kk = 0; kk < EE / 4; kk++) {
            float4 hv = hr[kk];
            c += hv.x * us[kk * 4] + hv.y * us[kk * 4 + 1] +
                 hv.z * us[kk * 4 + 2] + hv.w * us[kk * 4 + 3];
        }
        c *= m;
        c *= 0.0625f;
        logit = tanhf(c) * 10.0f;
    }
    float bm = blockReduceMax(logit, red);
    float e  = (t < LHN) ? __expf(logit - bm) : 0.0f;
    float bs = blockReduceSum(e, red);
    float p  = e / bs;
    float masked = (t < LHN) ? (p * m + 1e-20f) : 0.0f;
    float bs2 = blockReduceSum(masked, red);
    if (t < LHN) out[(size_t)b * LHN + t] = masked / bs2;
}

extern "C" void kernel_launch(void* const* d_in, const int* in_sizes, int n_in,
                              void* d_out, int out_size, void* d_ws, size_t ws_size,
                              hipStream_t stream) {
    const float* obs   = (const float*)d_in[0];
    const float* wi1   = (const float*)d_in[1];
    const float* bi1   = (const float*)d_in[2];
    const float* wi2   = (const float*)d_in[3];
    const float* bi2   = (const float*)d_in[4];
    const float* wl1   = (const float*)d_in[5];
    const float* bl1   = (const float*)d_in[6];
    const float* wl2   = (const float*)d_in[7];
    const float* bl2   = (const float*)d_in[8];
    const float* wn1   = (const float*)d_in[9];
    const float* bn1   = (const float*)d_in[10];
    const float* wn2   = (const float*)d_in[11];
    const float* bn2   = (const float*)d_in[12];
    const float* e_wq  = (const float*)d_in[13];
    const float* e_wk  = (const float*)d_in[14];
    const float* e_wv  = (const float*)d_in[15];
    const float* e_wo  = (const float*)d_in[16];
    const float* e_wf1 = (const float*)d_in[17];
    const float* e_bf1 = (const float*)d_in[18];
    const float* e_wf2 = (const float*)d_in[19];
    const float* e_bf2 = (const float*)d_in[20];
    const float* w_pn  = (const float*)d_in[21];
    const float* w_fc  = (const float*)d_in[22];
    float* outp = (float*)d_out;

    // ---- compact workspace layout: 254,017,536 B total ----
    char* wsc = (char*)d_ws;
    float* h    = (float*)wsc;
    u16*   hb   = (u16*)(wsc + 83886080);
    u16*   qaob = (u16*)(wsc + 125829120);   // qb, later aob
    u16*   kb   = (u16*)(wsc + 167772160);
    u16*   vt   = (u16*)(wsc + 209715200);
    u16*   wT   = (u16*)(wsc + 251658240);
    float* ubuf = (float*)(wsc + 253755392);
    u16*   hidb = kb;  // overlays kb+vt (disjoint lifetime)

    prep_kernel<<<dim3(512, 12), 256, 0, stream>>>(e_wq, e_wk, e_wv, e_wo, e_wf1, e_wf2, wT);
    pad_kernel<<<BB, 256, 0, stream>>>(h, hb);
    embed_seg<ILN, IHN, 0><<<IHN * BB / 32, 256, 0, stream>>>(obs, wi1, bi1, wi2, bi2, h, hb);
    embed_seg<8, LHN, IHN><<<LHN * BB / 32, 256, 0, stream>>>(obs, wl1, bl1, wl2, bl2, h, hb);
    embed_seg<6, 1, IHN + LHN><<<BB / 32, 256, 0, stream>>>(obs, wn1, bn1, wn2, bn2, h, hb);

    const size_t WL = 524288;
    for (int l = 0; l < NL; l++) {
        u16* wqkvT = wT + l * WL;
        u16* woT   = wqkvT + 196608;
        u16* w1T   = wqkvT + 262144;
        u16* w2T   = wqkvT + 393216;
        const float* bf1 = e_bf1 + (size_t)l * FFH;
        const float* bf2 = e_bf2 + (size_t)l * EE;

        qkv_gemm<<<dim3(MT / 128, 6), 256, 0, stream>>>(hb, wqkvT, qaob, kb, vt);
        attn_core<<<1280, 512, 0, stream>>>(qaob, kb, vt, obs, qaob);
        gemmln_kernel<4, 256, false><<<MT / 64, 512, 0, stream>>>(qaob, woT, nullptr, h, hb);
        ff1_gemm<<<dim3(MT / 128, 4), 256, 0, stream>>>(hb, w1T, bf1, hidb);
        gemmln_kernel<8, 512, true><<<MT / 64, 512, 0, stream>>>(hidb, w2T, bf2, h, hb);
    }
    final1_kernel<<<BB, 256, 0, stream>>>(h, obs, w_fc, w_pn, ubuf);
    final2_kernel<<<BB, 128, 0, stream>>>(h, obs, ubuf, outp);
}

// Round 12
// 615.509 us; speedup vs baseline: 1.6617x; 1.1378x over previous
//
#include <hip/hip_runtime.h>
#include <math.h>

static constexpr int BB   = 256;   // batch
static constexpr int IHN  = 200;   // internal tokens
static constexpr int ILN  = 6;     // internal feature dim
static constexpr int LHN  = 100;   // leaf tokens
static constexpr int EE   = 256;   // embed dim
static constexpr int FFH  = 512;   // ff hidden
static constexpr int NL   = 2;     // layers
static constexpr int GG   = 301;   // real tokens
static constexpr int GP   = 320;   // padded tokens (10 x 32)
static constexpr int MT   = BB * GP;  // 81920 total token rows

typedef unsigned short u16;
typedef short bf16x8 __attribute__((ext_vector_type(8)));
typedef float f32x4 __attribute__((ext_vector_type(4)));

#define MFMA(a, b, c) __builtin_amdgcn_mfma_f32_16x16x32_bf16((a), (b), (c), 0, 0, 0)

__device__ __forceinline__ u16 f2bf(float f) {
    union { float f; unsigned u; } v; v.f = f;
    unsigned r = v.u + 0x7FFFu + ((v.u >> 16) & 1u);
    return (u16)(r >> 16);
}

// ---------------- wave/block reduction helpers (wave = 64) ----------------
__device__ __forceinline__ float waveReduceSum(float v) {
    for (int o = 32; o > 0; o >>= 1) v += __shfl_down(v, o, 64);
    return v;
}
__device__ __forceinline__ float waveReduceMax(float v) {
    for (int o = 32; o > 0; o >>= 1) v = fmaxf(v, __shfl_down(v, o, 64));
    return v;
}
__device__ __forceinline__ float blockReduceSum(float v, float* red) {
    int lane = threadIdx.x & 63;
    int w    = threadIdx.x >> 6;
    int nw   = (blockDim.x + 63) >> 6;
    v = waveReduceSum(v);
    if (lane == 0) red[w] = v;
    __syncthreads();
    if (threadIdx.x < 64) {
        float x = (lane < nw) ? red[lane] : 0.0f;
        x = waveReduceSum(x);
        if (lane == 0) red[0] = x;
    }
    __syncthreads();
    float r = red[0];
    __syncthreads();
    return r;
}
__device__ __forceinline__ float blockReduceMax(float v, float* red) {
    int lane = threadIdx.x & 63;
    int w    = threadIdx.x >> 6;
    int nw   = (blockDim.x + 63) >> 6;
    v = waveReduceMax(v);
    if (lane == 0) red[w] = v;
    __syncthreads();
    if (threadIdx.x < 64) {
        float x = (lane < nw) ? red[lane] : -INFINITY;
        x = waveReduceMax(x);
        if (lane == 0) red[0] = x;
    }
    __syncthreads();
    float r = red[0];
    __syncthreads();
    return r;
}

// --------- staging: global -> LDS tile [rows][64] bf16, XOR-swizzled ---------
__device__ __forceinline__ void stage_swz(const u16* src, int strideShorts, int k0,
                                          u16* ldsTile, int nChunks, int wave,
                                          int nWaves, int lane)
{
    for (int c = wave; c < nChunks; c += nWaves) {
        int o = c * 1024 + lane * 16;
        int row = o >> 7;
        int cb = (o & 127) ^ ((row & 7) << 4);
        const u16* g = src + (size_t)row * strideShorts + k0 + (cb >> 1);
        __builtin_amdgcn_global_load_lds(
            (const __attribute__((address_space(1))) unsigned int*)g,
            (__attribute__((address_space(3))) unsigned int*)((char*)ldsTile + c * 1024),
            16, 0, 0);
    }
}

__device__ __forceinline__ bf16x8 lds_frag(const u16* tile, int row, int kk, int q)
{
    int cb = (kk * 64 + q * 16) ^ ((row & 7) << 4);
    return *(const bf16x8*)((const char*)tile + row * 128 + cb);
}

// ------------- prep: transpose encoder weights to bf16 [N][K] -------------
__global__ __launch_bounds__(256) void prep_kernel(
    const float* __restrict__ wq, const float* __restrict__ wk,
    const float* __restrict__ wv, const float* __restrict__ wo,
    const float* __restrict__ wf1, const float* __restrict__ wf2,
    u16* __restrict__ wT)
{
    int l = blockIdx.y / 6, m = blockIdx.y % 6;
    int idx = blockIdx.x * 256 + threadIdx.x;
    u16* dst = wT + (size_t)l * 524288;
    if (m < 4) {
        if (idx >= EE * EE) return;
        const float* src = (m == 0 ? wq : m == 1 ? wk : m == 2 ? wv : wo) + (size_t)l * EE * EE;
        int r = idx >> 8, c = idx & 255;
        dst[m * 65536 + idx] = f2bf(src[(size_t)c * EE + r]);
    } else if (m == 4) {
        if (idx >= FFH * EE) return;
        const float* src = wf1 + (size_t)l * EE * FFH;
        int r = idx >> 8, c = idx & 255;
        dst[262144 + idx] = f2bf(src[(size_t)c * FFH + r]);
    } else {
        if (idx >= EE * FFH) return;
        const float* src = wf2 + (size_t)l * FFH * EE;
        int r = idx >> 9, c = idx & 511;
        dst[393216 + idx] = f2bf(src[(size_t)c * EE + r]);
    }
}

// ---------- embed (segment version): 32 tokens/block, w2 col in regs ----------
template<int IND, int SEG, int G0>
__global__ __launch_bounds__(256) void embed_seg(
    const float* __restrict__ obs,
    const float* __restrict__ w1, const float* __restrict__ b1,
    const float* __restrict__ w2, const float* __restrict__ b2,
    float* __restrict__ h, u16* __restrict__ hb)
{
    __shared__ float xs[32][9];
    __shared__ float hid[32][33];
    int t = threadIdx.x;
    int fi0 = blockIdx.x * 32;

    for (int p = t; p < 32 * 9; p += 256) {
        int tok = p / 9, f = p % 9;
        int fi = fi0 + tok;
        int b = fi / SEG, g = G0 + fi % SEG;
        xs[tok][f] = obs[((size_t)b * GG + g) * 9 + f];
    }
    __syncthreads();

    #pragma unroll
    for (int p = 0; p < 4; p++) {
        int idx = p * 256 + t;
        int tok = idx >> 5, hcol = idx & 31;
        float a = b1[hcol];
        #pragma unroll
        for (int i = 0; i < IND; i++) a += xs[tok][i] * w1[i * 32 + hcol];
        hid[tok][hcol] = (a > 0.0f) ? a : 0.01f * a;
    }
    __syncthreads();

    float w2c[32];
    #pragma unroll
    for (int j = 0; j < 32; j++) w2c[j] = w2[j * EE + t];
    float bb = b2[t];
    for (int tok = 0; tok < 32; tok++) {
        int fi = fi0 + tok;
        int b = fi / SEG, g = G0 + fi % SEG;
        float a = bb;
        #pragma unroll
        for (int j = 0; j < 32; j++) a += hid[tok][j] * w2c[j];
        size_t o = ((size_t)b * GP + g) * EE + t;
        h[o] = a; hb[o] = f2bf(a);
    }
}

// zero the pad rows g in [GG, GP)
__global__ __launch_bounds__(256) void pad_kernel(float* __restrict__ h, u16* __restrict__ hb)
{
    int b = blockIdx.x, t = threadIdx.x;
    for (int g = GG; g < GP; g++) {
        size_t o = ((size_t)b * GP + g) * EE + t;
        h[o] = 0.0f; hb[o] = 0;
    }
}

// --------- QKV GEMM (A-in-regs): 128 rows/block, 8 waves, B streamed
// through 2x32KB LDS dbuf with counted vmcnt. Each wave: 16 rows, full K
// in regs (8 x bf16x8), per 64-col N-tile acc=4 f32x4 completed fully.
// 12 N-tiles: 0-3 -> qb, 4-7 -> kb, 8-11 -> vt (transposed scatter). ---------
__global__ __launch_bounds__(512) void qkv_gemm(
    const u16* __restrict__ hb, const u16* __restrict__ wqkvT,
    u16* __restrict__ qb, u16* __restrict__ kb, u16* __restrict__ vt)
{
    __shared__ __align__(16) u16 sB[2][16384];   // 2 x 32 KB (64n x 256k tile)
    int tid = threadIdx.x, lane = tid & 63, w = tid >> 6;   // w = 0..7
    int lr = lane & 15, q = lane >> 4, lk = q * 8;
    int brow = blockIdx.x * 128;

    // A rows (16 per wave) in registers: full K=256
    const u16* abase = hb + ((size_t)(brow + w * 16 + lr)) * 256;
    bf16x8 af[8];
    #pragma unroll
    for (int k8 = 0; k8 < 8; k8++) af[k8] = *(const bf16x8*)(abase + k8 * 32 + lk);

    // vt scatter coords (fixed per thread)
    int rowG0 = brow + w * 16 + q * 4;
    int b0 = rowG0 / GP, g0 = rowG0 - b0 * GP;

    // stage tile 0 (4 x 8KB sub-k tiles, 4 loads/thread)
    #pragma unroll
    for (int r = 0; r < 4; r++)
        stage_swz(wqkvT, 256, r * 64, sB[0] + r * 4096, 8, w, 8, lane);

    for (int nt = 0; nt < 12; nt++) {
        int cur = nt & 1;
        if (nt < 11) {
            #pragma unroll
            for (int r = 0; r < 4; r++)
                stage_swz(wqkvT + (size_t)(nt + 1) * 64 * 256, 256, r * 64,
                          sB[cur ^ 1] + r * 4096, 8, w, 8, lane);
            asm volatile("s_waitcnt vmcnt(4)" ::: "memory");
        } else {
            asm volatile("s_waitcnt vmcnt(0)" ::: "memory");
        }
        __builtin_amdgcn_s_barrier();

        f32x4 acc[4];
        #pragma unroll
        for (int n = 0; n < 4; n++) acc[n] = {0.0f, 0.0f, 0.0f, 0.0f};
        #pragma unroll
        for (int k8 = 0; k8 < 8; k8++) {
            bf16x8 a = af[k8];
            #pragma unroll
            for (int n = 0; n < 4; n++) {
                bf16x8 bb = lds_frag(sB[cur] + (k8 >> 1) * 4096, n * 16 + lr, k8 & 1, q);
                acc[n] = MFMA(a, bb, acc[n]);
            }
        }

        // epilogue for this tile
        if (nt < 8) {
            u16* dst = (nt < 4) ? qb : kb;
            int cOff = (nt & 3) * 64;
            #pragma unroll
            for (int n = 0; n < 4; n++) {
                int col = cOff + n * 16 + lr;
                #pragma unroll
                for (int j = 0; j < 4; j++)
                    dst[(size_t)(rowG0 + j) * 256 + col] = f2bf(acc[n][j]);
            }
        } else {
            #pragma unroll
            for (int n = 0; n < 4; n++) {
                int e = (nt - 8) * 64 + n * 16 + lr;
                ushort4 u4;
                u4.x = f2bf(acc[n][0]);
                u4.y = f2bf(acc[n][1]);
                u4.z = f2bf(acc[n][2]);
                u4.w = f2bf(acc[n][3]);
                *(ushort4*)(vt + ((size_t)(b0 * EE + e)) * GP + g0) = u4;
            }
        }
        __builtin_amdgcn_sched_barrier(0);
        __builtin_amdgcn_s_barrier();
    }
}

// --------- FF1 GEMM (A-in-regs): 128 rows/block, 8 waves, 8 N-tiles of 64,
//           epilogue bias+relu -> hidb bf16 ---------
__global__ __launch_bounds__(512) void ff1_gemm(
    const u16* __restrict__ hb, const u16* __restrict__ w1T,
    const float* __restrict__ bf1, u16* __restrict__ hidb)
{
    __shared__ __align__(16) u16 sB[2][16384];
    int tid = threadIdx.x, lane = tid & 63, w = tid >> 6;
    int lr = lane & 15, q = lane >> 4, lk = q * 8;
    int brow = blockIdx.x * 128;

    const u16* abase = hb + ((size_t)(brow + w * 16 + lr)) * 256;
    bf16x8 af[8];
    #pragma unroll
    for (int k8 = 0; k8 < 8; k8++) af[k8] = *(const bf16x8*)(abase + k8 * 32 + lk);

    int rowG0 = brow + w * 16 + q * 4;

    #pragma unroll
    for (int r = 0; r < 4; r++)
        stage_swz(w1T, 256, r * 64, sB[0] + r * 4096, 8, w, 8, lane);

    for (int nt = 0; nt < 8; nt++) {
        int cur = nt & 1;
        if (nt < 7) {
            #pragma unroll
            for (int r = 0; r < 4; r++)
                stage_swz(w1T + (size_t)(nt + 1) * 64 * 256, 256, r * 64,
                          sB[cur ^ 1] + r * 4096, 8, w, 8, lane);
            asm volatile("s_waitcnt vmcnt(4)" ::: "memory");
        } else {
            asm volatile("s_waitcnt vmcnt(0)" ::: "memory");
        }
        __builtin_amdgcn_s_barrier();

        f32x4 acc[4];
        #pragma unroll
        for (int n = 0; n < 4; n++) acc[n] = {0.0f, 0.0f, 0.0f, 0.0f};
        #pragma unroll
        for (int k8 = 0; k8 < 8; k8++) {
            bf16x8 a = af[k8];
            #pragma unroll
            for (int n = 0; n < 4; n++) {
                bf16x8 bb = lds_frag(sB[cur] + (k8 >> 1) * 4096, n * 16 + lr, k8 & 1, q);
                acc[n] = MFMA(a, bb, acc[n]);
            }
        }

        #pragma unroll
        for (int n = 0; n < 4; n++) {
            int col = nt * 64 + n * 16 + lr;
            float bias = bf1[col];
            #pragma unroll
            for (int j = 0; j < 4; j++) {
                float v = acc[n][j] + bias;
                hidb[(size_t)(rowG0 + j) * 512 + col] = f2bf(fmaxf(v, 0.0f));
            }
        }
        __builtin_amdgcn_sched_barrier(0);
        __builtin_amdgcn_s_barrier();
    }
}

// ---- GEMM + residual + LayerNorm: BM=64, BN=256(full row), 8 waves,
//      dbuf counted-vmcnt staging. STR = K = A-stride = B-stride. ----
template<int KSTEPS, int STR, bool HASB>
__global__ __launch_bounds__(512) void gemmln_kernel(
    const u16* __restrict__ A, const u16* __restrict__ Bw,
    const float* __restrict__ bias, float* __restrict__ h, u16* __restrict__ hb)
{
    __shared__ __align__(16) u16 sA[2][64 * 64];    // 2 x 8 KB
    __shared__ __align__(16) u16 sB[2][256 * 64];   // 2 x 32 KB
    int tid = threadIdx.x, lane = tid & 63, w = tid >> 6;
    int wm = w >> 2, wn = w & 3;
    int lr = lane & 15, q = lane >> 4;
    int brow = blockIdx.x * 64;

    f32x4 acc[2][4];
    #pragma unroll
    for (int i = 0; i < 2; i++)
        #pragma unroll
        for (int j = 0; j < 4; j++) acc[i][j] = {0.0f, 0.0f, 0.0f, 0.0f};

    stage_swz(A + (size_t)brow * STR, STR, 0, sA[0], 8, w, 8, lane);
    stage_swz(Bw, STR, 0, sB[0], 32, w, 8, lane);

    for (int ks = 0; ks < KSTEPS; ks++) {
        int cur = ks & 1;
        if (ks + 1 < KSTEPS) {
            stage_swz(A + (size_t)brow * STR, STR, (ks + 1) * 64, sA[cur ^ 1], 8, w, 8, lane);
            stage_swz(Bw, STR, (ks + 1) * 64, sB[cur ^ 1], 32, w, 8, lane);
            asm volatile("s_waitcnt vmcnt(5)" ::: "memory");
        } else {
            asm volatile("s_waitcnt vmcnt(0)" ::: "memory");
        }
        __builtin_amdgcn_s_barrier();
        #pragma unroll
        for (int kk = 0; kk < 2; kk++) {
            bf16x8 a[2], b[4];
            #pragma unroll
            for (int i = 0; i < 2; i++)
                a[i] = lds_frag(sA[cur], wm * 32 + i * 16 + lr, kk, q);
            #pragma unroll
            for (int n = 0; n < 4; n++)
                b[n] = lds_frag(sB[cur], wn * 64 + n * 16 + lr, kk, q);
            #pragma unroll
            for (int mi = 0; mi < 2; mi++)
                #pragma unroll
                for (int ni = 0; ni < 4; ni++)
                    acc[mi][ni] = MFMA(a[mi], b[ni], acc[mi][ni]);
        }
        __builtin_amdgcn_sched_barrier(0);
        __builtin_amdgcn_s_barrier();
    }

    __syncthreads();
    float* sPart = (float*)sA;           // [4 wn][64 row][2] = 2 KB

    #pragma unroll
    for (int ni = 0; ni < 4; ni++) {
        int col = wn * 64 + ni * 16 + lr;
        float bv = HASB ? bias[col] : 0.0f;
        #pragma unroll
        for (int mi = 0; mi < 2; mi++)
            #pragma unroll
            for (int j = 0; j < 4; j++) {
                int rowG = brow + wm * 32 + mi * 16 + q * 4 + j;
                acc[mi][ni][j] += bv + h[(size_t)rowG * 256 + col];
            }
    }
    #pragma unroll
    for (int mi = 0; mi < 2; mi++)
        #pragma unroll
        for (int j = 0; j < 4; j++) {
            float s1 = 0.0f, s2 = 0.0f;
            #pragma unroll
            for (int ni = 0; ni < 4; ni++) {
                float v = acc[mi][ni][j];
                s1 += v; s2 += v * v;
            }
            s1 += __shfl_xor(s1, 1); s2 += __shfl_xor(s2, 1);
            s1 += __shfl_xor(s1, 2); s2 += __shfl_xor(s2, 2);
            s1 += __shfl_xor(s1, 4); s2 += __shfl_xor(s2, 4);
            s1 += __shfl_xor(s1, 8); s2 += __shfl_xor(s2, 8);
            if (lr == 0) {
                int lrow = wm * 32 + mi * 16 + q * 4 + j;
                sPart[(wn * 64 + lrow) * 2 + 0] = s1;
                sPart[(wn * 64 + lrow) * 2 + 1] = s2;
            }
        }
    __syncthreads();

    #pragma unroll
    for (int mi = 0; mi < 2; mi++)
        #pragma unroll
        for (int j = 0; j < 4; j++) {
            int lrow = wm * 32 + mi * 16 + q * 4 + j;
            float s1 = sPart[lrow * 2] + sPart[(64 + lrow) * 2] +
                       sPart[(128 + lrow) * 2] + sPart[(192 + lrow) * 2];
            float s2 = sPart[lrow * 2 + 1] + sPart[(64 + lrow) * 2 + 1] +
                       sPart[(128 + lrow) * 2 + 1] + sPart[(192 + lrow) * 2 + 1];
            float mean = s1 * (1.0f / 256.0f);
            float var  = s2 * (1.0f / 256.0f) - mean * mean;
            float rstd = rsqrtf(var + 1e-5f);
            int rowG = brow + lrow;
            #pragma unroll
            for (int ni = 0; ni < 4; ni++) {
                int col = wn * 64 + ni * 16 + lr;
                float v = (acc[mi][ni][j] - mean) * rstd;
                size_t o = (size_t)rowG * 256 + col;
                h[o] = v; hb[o] = f2bf(v);
            }
        }
}

// ------- attention core (flash-LDS, 2 blocks/CU): K/V staged via
// global_load_lds with counted-vmcnt prefetch; two-pass softmax; P kept
// packed-bf16 in REGISTERS and written per-tile to a single 9 KB LDS tile
// (stride 72 -> 2-way banks). LDS total ~77 KB -> 2 blocks/CU.
// 64 q-rows/block, 512 thr (8 waves: wm row-quarter, wn j/e-half).
// aob may alias qb: Q read into regs at block start, aob written at end.
__global__ __launch_bounds__(512) void attn_core(
    const u16* __restrict__ qb, const u16* __restrict__ kb,
    const u16* __restrict__ vt, const float* __restrict__ obs,
    u16* __restrict__ aob)
{
    __shared__ __align__(16) u16 sKV[2][16384];   // 64 KB: K tiles, then V tiles
    __shared__ __align__(16) u16 sPt[64 * 72];    // 9 KB: one 64-key P tile
    __shared__ float sBias[320];
    __shared__ float sPm[2][64], sPs[2][64];

    int id = blockIdx.x;                 // 1280 blocks
    int xcd = id & 7, jj = id >> 3;      // jj in [0,160)
    int tile = jj % 5, bgrp = jj / 5;    // bgrp in [0,32)
    int b = xcd + 8 * bgrp;              // bijective batch
    int t0 = tile * 64;

    int tid = threadIdx.x, w = tid >> 6, lane = tid & 63;
    int wm = w >> 1, wn = w & 1;         // row-quarter (16 rows), j/e-half
    int lr = lane & 15, q = lane >> 4, lk = q * 8;

    if (tid < 320) {
        float msk = (tid < GG) ? obs[((size_t)b * GG + tid) * 9 + 8] : 0.0f;
        sBias[tid] = (1.0f - msk) * -1e9f;
    }

    // Q fragments for this wave's 16 rows: 8 x bf16x8 (all 256 k)
    const u16* qbase = qb + ((size_t)(b * GP + t0 + wm * 16 + lr)) * 256;
    bf16x8 af[8];
    #pragma unroll
    for (int k8 = 0; k8 < 8; k8++) af[k8] = *(const bf16x8*)(qbase + k8 * 32 + lk);

    const u16* vbase = vt + (size_t)b * EE * GP;

    // ---- scores: 5 K-tiles of 64 keys, double-buffered, counted vmcnt ----
    #pragma unroll
    for (int r = 0; r < 4; r++)
        stage_swz(kb + ((size_t)b * GP) * 256, 256, r * 64, sKV[0] + r * 4096, 8, w, 8, lane);

    f32x4 sacc[10];
    #pragma unroll
    for (int s = 0; s < 10; s++) sacc[s] = {0.0f, 0.0f, 0.0f, 0.0f};

    #pragma unroll
    for (int t = 0; t < 5; t++) {
        if (t < 4) {
            #pragma unroll
            for (int r = 0; r < 4; r++)
                stage_swz(kb + ((size_t)(b * GP + (t + 1) * 64)) * 256, 256, r * 64,
                          sKV[(t + 1) & 1] + r * 4096, 8, w, 8, lane);
            asm volatile("s_waitcnt vmcnt(4)" ::: "memory");
        } else {
            asm volatile("s_waitcnt vmcnt(0)" ::: "memory");
        }
        __builtin_amdgcn_s_barrier();
        const u16* kbuf = sKV[t & 1];
        #pragma unroll
        for (int ks = 0; ks < 4; ks++)
            #pragma unroll
            for (int kk = 0; kk < 2; kk++) {
                bf16x8 a = af[ks * 2 + kk];
                #pragma unroll
                for (int l = 0; l < 2; l++) {
                    int jl = (wn * 2 + l) * 16 + lr;
                    bf16x8 bb = lds_frag(kbuf + ks * 4096, jl, kk, q);
                    sacc[t * 2 + l] = MFMA(a, bb, sacc[t * 2 + l]);
                }
            }
        __builtin_amdgcn_s_barrier();
    }

    // ---- bias + row max (two partials over wn) ----
    #pragma unroll
    for (int s = 0; s < 10; s++) {
        int j = (s >> 1) * 64 + (wn * 2 + (s & 1)) * 16 + lr;
        float bia = sBias[j];
        #pragma unroll
        for (int r = 0; r < 4; r++) sacc[s][r] = sacc[s][r] * 0.0625f + bia;
    }
    #pragma unroll
    for (int r = 0; r < 4; r++) {
        float mx = -1e30f;
        #pragma unroll
        for (int s = 0; s < 10; s++) mx = fmaxf(mx, sacc[s][r]);
        mx = fmaxf(mx, __shfl_xor(mx, 1));
        mx = fmaxf(mx, __shfl_xor(mx, 2));
        mx = fmaxf(mx, __shfl_xor(mx, 4));
        mx = fmaxf(mx, __shfl_xor(mx, 8));
        if (lr == 0) sPm[wn][wm * 16 + q * 4 + r] = mx;
    }
    __syncthreads();   // no vmem outstanding here (K loop drained to 0)

    // prefetch V0 into buf0 (K compute fully done); softmax hides its latency
    stage_swz(vbase, GP, 0 * 64, sKV[0], 32, w, 8, lane);

    #pragma unroll
    for (int r = 0; r < 4; r++) {
        int row = wm * 16 + q * 4 + r;
        float rm = fmaxf(sPm[0][row], sPm[1][row]);
        float ss = 0.0f;
        #pragma unroll
        for (int s = 0; s < 10; s++) {
            float e = __expf(sacc[s][r] - rm);
            sacc[s][r] = e;
            ss += e;
        }
        ss += __shfl_xor(ss, 1);
        ss += __shfl_xor(ss, 2);
        ss += __shfl_xor(ss, 4);
        ss += __shfl_xor(ss, 8);
        if (lr == 0) sPs[wn][row] = ss;
    }
    // lgkm-only barrier: must NOT drain vmcnt (V0 prefetch in flight)
    asm volatile("s_waitcnt lgkmcnt(0)" ::: "memory");
    __builtin_amdgcn_s_barrier();
    __builtin_amdgcn_sched_barrier(0);

    // ---- normalize + pack P to bf16 pairs in registers (frees sacc) ----
    float invr[4];
    #pragma unroll
    for (int r = 0; r < 4; r++) {
        int row = wm * 16 + q * 4 + r;
        invr[r] = 1.0f / (sPs[0][row] + sPs[1][row]);
    }
    unsigned pk[10][2];
    #pragma unroll
    for (int s = 0; s < 10; s++) {
        pk[s][0] = (unsigned)f2bf(sacc[s][0] * invr[0]) |
                   ((unsigned)f2bf(sacc[s][1] * invr[1]) << 16);
        pk[s][1] = (unsigned)f2bf(sacc[s][2] * invr[2]) |
                   ((unsigned)f2bf(sacc[s][3] * invr[3]) << 16);
    }

    // ---- PV: 5 V-tiles of 64 keys (V^T [256 e][64 g]), dbuf; P tile
    //      written from regs just-in-time into the single sPt buffer ----
    f32x4 oacc[8];
    #pragma unroll
    for (int n = 0; n < 8; n++) oacc[n] = {0.0f, 0.0f, 0.0f, 0.0f};

    #pragma unroll
    for (int c = 0; c < 5; c++) {
        if (c < 4) {
            stage_swz(vbase, GP, (c + 1) * 64, sKV[(c + 1) & 1], 32, w, 8, lane);
            asm volatile("s_waitcnt vmcnt(4)" ::: "memory");
        } else {
            asm volatile("s_waitcnt vmcnt(0)" ::: "memory");
        }
        __builtin_amdgcn_s_barrier();   // V_c ready; prev MFMA reads done; sPt free
        // write this tile's P slice (keys c*64..c*64+63)
        #pragma unroll
        for (int sl = 0; sl < 2; sl++) {
            int jl = (wn * 2 + sl) * 16 + lr;
            #pragma unroll
            for (int r = 0; r < 4; r++) {
                int row = wm * 16 + q * 4 + r;
                unsigned v = pk[c * 2 + sl][r >> 1];
                sPt[row * 72 + jl] = (u16)((r & 1) ? (v >> 16) : (v & 0xffffu));
            }
        }
        asm volatile("s_waitcnt lgkmcnt(0)" ::: "memory");
        __builtin_amdgcn_s_barrier();
        __builtin_amdgcn_sched_barrier(0);
        #pragma unroll
        for (int kk = 0; kk < 2; kk++) {
            bf16x8 a = *(const bf16x8*)(sPt + (wm * 16 + lr) * 72 + kk * 32 + lk);
            #pragma unroll
            for (int n = 0; n < 8; n++) {
                bf16x8 vv = lds_frag(sKV[c & 1], wn * 128 + n * 16 + lr, kk, q);
                oacc[n] = MFMA(a, vv, oacc[n]);
            }
        }
        __builtin_amdgcn_s_barrier();
    }

    #pragma unroll
    for (int n = 0; n < 8; n++) {
        int col = wn * 128 + n * 16 + lr;
        #pragma unroll
        for (int r = 0; r < 4; r++) {
            int row = wm * 16 + q * 4 + r;
            aob[((size_t)(b * GP + t0 + row)) * 256 + col] = f2bf(oacc[n][r]);
        }
    }
}

// ------------- head part 1: graph embed -> fixed context -> u[b] -------------
__global__ __launch_bounds__(256) void final1_kernel(
    const float* __restrict__ h, const float* __restrict__ obs,
    const float* __restrict__ w_fc, const float* __restrict__ w_pn,
    float* __restrict__ u)
{
    int b = blockIdx.x;
    int t = threadIdx.x;
    __shared__ float ges[EE];
    __shared__ float fcs[EE];

    float acc = 0.0f, vlen = 0.0f;
    for (int g = 0; g < GG; g++) {
        float m = obs[((size_t)b * GG + g) * 9 + 8];
        vlen += m;
        acc += h[((size_t)b * GP + g) * EE + t] * m;
    }
    ges[t] = acc / vlen;
    __syncthreads();

    float fc = 0.0f;
    for (int kk = 0; kk < EE; kk++) fc += ges[kk] * w_fc[kk * EE + t];
    fcs[t] = fc;
    __syncthreads();

    const float4* wp = reinterpret_cast<const float4*>(w_pn + (size_t)t * 3 * EE);
    float ua = 0.0f;
    for (int kk = 0; kk < EE / 4; kk++) {
        float4 w = wp[kk];
        ua += w.x * fcs[kk * 4] + w.y * fcs[kk * 4 + 1] +
              w.z * fcs[kk * 4 + 2] + w.w * fcs[kk * 4 + 3];
    }
    u[(size_t)b * EE + t] = ua;
}

// ------------- head part 2: compat -> tanh clip -> masked softmax -------------
__global__ __launch_bounds__(128) void final2_kernel(
    const float* __restrict__ h, const float* __restrict__ obs,
    const float* __restrict__ u, float* __restrict__ out)
{
    int b = blockIdx.x;
    int t = threadIdx.x;
    __shared__ float us[EE];
    __shared__ float red[8];
    us[t]       = u[(size_t)b * EE + t];
    us[t + 128] = u[(size_t)b * EE + t + 128];
    __syncthreads();

    float logit = -INFINITY;
    float m = 0.0f;
    if (t < LHN) {
        int g = IHN + t;
        m = obs[((size_t)b * GG + g) * 9 + 8];
        const float4* hr = reinterpret_cast<const float4*>(h + ((size_t)b * GP + g) * EE);
        float c = 0.0f;
        for (int kk = 0; kk < EE / 4; kk++) {
            float4 hv = hr[kk];
            c += hv.x * us[kk * 4] + hv.y * us[kk * 4 + 1] +
                 hv.z * us[kk * 4 + 2] + hv.w * us[kk * 4 + 3];
        }
        c *= m;
        c *= 0.0625f;
        logit = tanhf(c) * 10.0f;
    }
    float bm = blockReduceMax(logit, red);
    float e  = (t < LHN) ? __expf(logit - bm) : 0.0f;
    float bs = blockReduceSum(e, red);
    float p  = e / bs;
    float masked = (t < LHN) ? (p * m + 1e-20f) : 0.0f;
    float bs2 = blockReduceSum(masked, red);
    if (t < LHN) out[(size_t)b * LHN + t] = masked / bs2;
}

extern "C" void kernel_launch(void* const* d_in, const int* in_sizes, int n_in,
                              void* d_out, int out_size, void* d_ws, size_t ws_size,
                              hipStream_t stream) {
    const float* obs   = (const float*)d_in[0];
    const float* wi1   = (const float*)d_in[1];
    const float* bi1   = (const float*)d_in[2];
    const float* wi2   = (const float*)d_in[3];
    const float* bi2   = (const float*)d_in[4];
    const float* wl1   = (const float*)d_in[5];
    const float* bl1   = (const float*)d_in[6];
    const float* wl2   = (const float*)d_in[7];
    const float* bl2   = (const float*)d_in[8];
    const float* wn1   = (const float*)d_in[9];
    const float* bn1   = (const float*)d_in[10];
    const float* wn2   = (const float*)d_in[11];
    const float* bn2   = (const float*)d_in[12];
    const float* e_wq  = (const float*)d_in[13];
    const float* e_wk  = (const float*)d_in[14];
    const float* e_wv  = (const float*)d_in[15];
    const float* e_wo  = (const float*)d_in[16];
    const float* e_wf1 = (const float*)d_in[17];
    const float* e_bf1 = (const float*)d_in[18];
    const float* e_wf2 = (const float*)d_in[19];
    const float* e_bf2 = (const float*)d_in[20];
    const float* w_pn  = (const float*)d_in[21];
    const float* w_fc  = (const float*)d_in[22];
    float* outp = (float*)d_out;

    // ---- compact workspace layout: 254,017,536 B total ----
    char* wsc = (char*)d_ws;
    float* h    = (float*)wsc;
    u16*   hb   = (u16*)(wsc + 83886080);
    u16*   qaob = (u16*)(wsc + 125829120);   // qb, later aob
    u16*   kb   = (u16*)(wsc + 167772160);
    u16*   vt   = (u16*)(wsc + 209715200);
    u16*   wT   = (u16*)(wsc + 251658240);
    float* ubuf = (float*)(wsc + 253755392);
    u16*   hidb = kb;  // overlays kb+vt (disjoint lifetime)

    prep_kernel<<<dim3(512, 12), 256, 0, stream>>>(e_wq, e_wk, e_wv, e_wo, e_wf1, e_wf2, wT);
    pad_kernel<<<BB, 256, 0, stream>>>(h, hb);
    embed_seg<ILN, IHN, 0><<<IHN * BB / 32, 256, 0, stream>>>(obs, wi1, bi1, wi2, bi2, h, hb);
    embed_seg<8, LHN, IHN><<<LHN * BB / 32, 256, 0, stream>>>(obs, wl1, bl1, wl2, bl2, h, hb);
    embed_seg<6, 1, IHN + LHN><<<BB / 32, 256, 0, stream>>>(obs, wn1, bn1, wn2, bn2, h, hb);

    const size_t WL = 524288;
    for (int l = 0; l < NL; l++) {
        u16* wqkvT = wT + l * WL;
        u16* woT   = wqkvT + 196608;
        u16* w1T   = wqkvT + 262144;
        u16* w2T   = wqkvT + 393216;
        const float* bf1 = e_bf1 + (size_t)l * FFH;
        const float* bf2 = e_bf2 + (size_t)l * EE;

        qkv_gemm<<<MT / 128, 512, 0, stream>>>(hb, wqkvT, qaob, kb, vt);
        attn_core<<<1280, 512, 0, stream>>>(qaob, kb, vt, obs, qaob);
        gemmln_kernel<4, 256, false><<<MT / 64, 512, 0, stream>>>(qaob, woT, nullptr, h, hb);
        ff1_gemm<<<MT / 128, 512, 0, stream>>>(hb, w1T, bf1, hidb);
        gemmln_kernel<8, 512, true><<<MT / 64, 512, 0, stream>>>(hidb, w2T, bf2, h, hb);
    }
    final1_kernel<<<BB, 256, 0, stream>>>(h, obs, w_fc, w_pn, ubuf);
    final2_kernel<<<BB, 128, 0, stream>>>(h, obs, ubuf, outp);
}